// Round 10
// baseline (275.184 us; speedup 1.0000x reference)
//
#include <hip/hip_runtime.h>

#define H_N 28
#define KVH_N 4
#define D_N 128
#define S_N 2048
#define E_N 3584
#define NQKV 4608

typedef unsigned short u16;
typedef unsigned int u32;
typedef __bf16 bf16x8 __attribute__((ext_vector_type(8)));
typedef float f32x4 __attribute__((ext_vector_type(4)));
typedef float f32x16 __attribute__((ext_vector_type(16)));
typedef unsigned short u16x4 __attribute__((ext_vector_type(4)));
typedef unsigned short u16x8 __attribute__((ext_vector_type(8)));
typedef unsigned int u32x2 __attribute__((ext_vector_type(2)));
typedef unsigned int u32x4 __attribute__((ext_vector_type(4)));

typedef __attribute__((address_space(1))) void gvoid_t;
typedef __attribute__((address_space(3))) void lvoid_t;

static __device__ __forceinline__ u16 f2bf(float f) {
  __bf16 h = (__bf16)f;
  return __builtin_bit_cast(unsigned short, h);
}

static __device__ __forceinline__ float bf2f(u16 b) {
  u32 u = (u32)b << 16;
  return __builtin_bit_cast(float, u);
}

static __device__ __forceinline__ void gload16(const void* g, void* l) {
  __builtin_amdgcn_global_load_lds((gvoid_t*)g, (lvoid_t*)l, 16, 0, 0);
}

static __device__ __forceinline__ u32 cvt_pk_bf16(float lo, float hi) {
  u32 r;
  asm("v_cvt_pk_bf16_f32 %0, %1, %2" : "=v"(r) : "v"(lo), "v"(hi));
  return r;
}

static __device__ __forceinline__ void pl32swap(u32& a, u32& b) {
  asm volatile("v_permlane32_swap_b32 %0, %1" : "+v"(a), "+v"(b));
}

static __device__ __forceinline__ float vmax16(f32x16 v) {
  float a = fmaxf(fmaxf(v[0], v[1]), fmaxf(v[2], v[3]));
  float b = fmaxf(fmaxf(v[4], v[5]), fmaxf(v[6], v[7]));
  float c = fmaxf(fmaxf(v[8], v[9]), fmaxf(v[10], v[11]));
  float d = fmaxf(fmaxf(v[12], v[13]), fmaxf(v[14], v[15]));
  return fmaxf(fmaxf(a, b), fmaxf(c, d));
}

static __device__ __forceinline__ float vsum16(f32x16 v) {
  float a = (v[0] + v[1]) + (v[2] + v[3]);
  float b = (v[4] + v[5]) + (v[6] + v[7]);
  float c = (v[8] + v[9]) + (v[10] + v[11]);
  float d = (v[12] + v[13]) + (v[14] + v[15]);
  return (a + b) + (c + d);
}

// ---------------- hs f32 -> bf16, GEMM-swizzled (8-elem group ^= row&7) ----------------
__global__ __launch_bounds__(256) void k_hs_bf16_swz(const float* __restrict__ in,
                                                     u16* __restrict__ out) {
  int g = blockIdx.x * 256 + threadIdx.x;  // 2048*3584/8 groups
  int row = g / 448, c8 = g % 448;
  const float4* p = (const float4*)(in + (size_t)g * 8);
  float4 a = p[0], b = p[1];
  u16x8 r;
  r[0] = f2bf(a.x); r[1] = f2bf(a.y); r[2] = f2bf(a.z); r[3] = f2bf(a.w);
  r[4] = f2bf(b.x); r[5] = f2bf(b.y); r[6] = f2bf(b.z); r[7] = f2bf(b.w);
  int dc8 = c8 ^ (row & 7);
  *(u16x8*)(out + (size_t)row * E_N + dc8 * 8) = r;
}

// ---------------- transpose f32 [R][C] -> bf16 [C][R], GEMM-swizzled rows ----------------
__global__ __launch_bounds__(256) void k_transpose_bf16(const float* __restrict__ in,
                                                        u16* __restrict__ out,
                                                        int R, int C) {
  __shared__ float t[64][65];
  int r0 = blockIdx.y * 64, c0 = blockIdx.x * 64;
  int lr = threadIdx.x >> 6, lc = threadIdx.x & 63;
#pragma unroll
  for (int i = 0; i < 64; i += 4)
    t[lr + i][lc] = in[(size_t)(r0 + lr + i) * C + c0 + lc];
  __syncthreads();
#pragma unroll
  for (int i = 0; i < 64; i += 4) {
    int orow = c0 + lr + i;
    int sw = (orow & 7) << 3;
    out[(size_t)orow * R + r0 + (lc ^ sw)] = f2bf(t[lc][lr + i]);
  }
}

// =================== GEMM BMx256, BK=64, 8 waves, 2-barrier counted-vmcnt ==============
// A[M,K], Bt[N,K] bf16 pre-swizzled (8-elem group ^= row&7 per 64-span).
// Per tile T: {compute T (compiler-scheduled ds_read+MFMA); LGKM0; BARR;
//              stage T+2 -> buf cur; vmcnt(UNITS) [tile T+1 resident]; BARR}
// The counted wait covers writes that had a full tile of compute to land (no drain).
// Stage-into-buf-cur is issued only after all waves' reads of it are drained.
// EPI=1: fused QKV epilogue (Q [h][s][d]; K [kvh][s][d] pre-rope; V transposed+swz).
#define BARR __builtin_amdgcn_s_barrier()
#define SB0 __builtin_amdgcn_sched_barrier(0)
#define LGKM0 asm volatile("s_waitcnt lgkmcnt(0)" ::: "memory")
#define VMW7 asm volatile("s_waitcnt vmcnt(7)" ::: "memory")
#define VMW6 asm volatile("s_waitcnt vmcnt(6)" ::: "memory")
#define VMW0 asm volatile("s_waitcnt vmcnt(0)" ::: "memory")

template <int BM, int EPI>
__global__ __launch_bounds__(512, 2) void k_gemm(const u16* __restrict__ A,
                                                 const u16* __restrict__ Bt,
                                                 float* __restrict__ Cout,
                                                 int Nn, int nxt,
                                                 const float* __restrict__ qb,
                                                 const float* __restrict__ kb,
                                                 const float* __restrict__ vb,
                                                 u16* __restrict__ Qo,
                                                 u16* __restrict__ Ko,
                                                 u16* __restrict__ Vo) {
  constexpr int NA = BM / 64;   // A stage units (3 or 2)
  constexpr int MH = NA;        // m-frags per half per wave
  constexpr int UNITS = NA + 4;
  constexpr int LROWS = BM + 256;
  __shared__ __align__(16) u16 L[2 * LROWS * 64];
  const int K = 3584, NKT = 56;
  const int tid = threadIdx.x;
  const int lane = tid & 63;
  const int w = tid >> 6;
  const int lr = lane & 15, lh = lane >> 4, lh8 = lh * 8;
  const int swz = (lr & 7) << 3;
  const int wr = w >> 2, wc = w & 3;  // 2 M-waves x 4 N-waves

  // bijective XCD swizzle (m204)
  const int nwg = gridDim.x;
  const int bid = blockIdx.x;
  const int q8 = nwg >> 3, r8 = nwg & 7;
  const int xcd = bid & 7, idx = bid >> 3;
  const int lb = (xcd < r8 ? xcd * (q8 + 1) : r8 * (q8 + 1) + (xcd - r8) * q8) + idx;
  const size_t m0 = (size_t)(lb / nxt) * BM;
  const size_t n0 = (size_t)(lb % nxt) << 8;

  const u16* __restrict__ Ab = A + m0 * K;
  const u16* __restrict__ Bb = Bt + n0 * K;

  const int srow = tid >> 3, scol8 = tid & 7;
  auto stg = [&](int buf, int u, int kt) {
    if (kt >= NKT) return;
    const u16* src;
    int ldsrow;
    if (u < NA) {
      src = Ab + (size_t)(u * 64 + srow) * K;
      ldsrow = u * 64 + srow;
    } else {
      src = Bb + (size_t)((u - NA) * 64 + srow) * K;
      ldsrow = BM + (u - NA) * 64 + srow;
    }
    gload16(src + kt * 64 + scol8 * 8, &L[buf * (LROWS * 64) + ldsrow * 64 + scol8 * 8]);
  };

  f32x4 acc[2 * MH][4];
#pragma unroll
  for (int i = 0; i < 2 * MH; i++)
#pragma unroll
    for (int j = 0; j < 4; j++) acc[i][j] = f32x4{0.f, 0.f, 0.f, 0.f};

  bf16x8 afA[MH][2], afB[MH][2], bq[2][2];

  auto rdA = [&](bf16x8(&arr)[MH][2], int LB, int mbase) {
#pragma unroll
    for (int mm = 0; mm < MH; ++mm)
#pragma unroll
      for (int kk = 0; kk < 2; ++kk)
        arr[mm][kk] = *(const bf16x8*)&L[LB + (wr * (BM / 2) + (mbase + mm) * 16 + lr) * 64 +
                                         ((kk * 32 + lh8) ^ swz)];
  };
  auto rdB = [&](int LB, int qbase) {
#pragma unroll
    for (int j = 0; j < 2; ++j)
#pragma unroll
      for (int kk = 0; kk < 2; ++kk)
        bq[j][kk] = *(const bf16x8*)&L[LB + (BM + (qbase + j) * 64 + wc * 16 + lr) * 64 +
                                       ((kk * 32 + lh8) ^ swz)];
  };
  auto mm4 = [&](bf16x8(&af)[MH][2], int mbase, int qbase) {
    __builtin_amdgcn_s_setprio(1);
#pragma unroll
    for (int mm = 0; mm < MH; ++mm)
#pragma unroll
      for (int j = 0; j < 2; ++j)
#pragma unroll
        for (int kk = 0; kk < 2; ++kk)
          acc[mbase + mm][qbase + j] = __builtin_amdgcn_mfma_f32_16x16x32_bf16(
              af[mm][kk], bq[j][kk], acc[mbase + mm][qbase + j], 0, 0, 0);
    __builtin_amdgcn_s_setprio(0);
  };

  // prologue: tile0 -> buf0, tile1 -> buf1; counted wait leaves tile1 in flight.
#pragma unroll
  for (int u = 0; u < UNITS; ++u) stg(0, u, 0);
#pragma unroll
  for (int u = 0; u < UNITS; ++u) stg(1, u, 1);
  if constexpr (UNITS == 7) { VMW7; } else { VMW6; }
  SB0; BARR; SB0;

  for (int T = 0; T < NKT; ++T) {
    const int cur = T & 1;
    const int LB = cur * (LROWS * 64);
    // ---- compute tile T: compiler-scheduled reads + MFMA ----
    rdA(afA, LB, 0);
    rdB(LB, 0);
    mm4(afA, 0, 0);
    rdA(afB, LB, MH);
    mm4(afB, MH, 0);
    rdB(LB, 2);
    mm4(afA, 0, 2);
    mm4(afB, MH, 2);
    // ---- all reads of buf cur drained; then restage it ----
    LGKM0; SB0; BARR; SB0;
#pragma unroll
    for (int u = 0; u < UNITS; ++u) stg(cur, u, T + 2);
    if (T + 2 < NKT) {
      if constexpr (UNITS == 7) { VMW7; } else { VMW6; }
    } else {
      VMW0;
    }
    SB0; BARR; SB0;
  }

  if constexpr (EPI == 0) {
    const size_t Nsz = (size_t)Nn;
#pragma unroll
    for (int m = 0; m < 2 * MH; ++m) {
      size_t row = m0 + wr * (BM / 2) + m * 16 + lh * 4;
      if (row < 2048) {
#pragma unroll
        for (int p = 0; p < 4; ++p) {
          size_t col = n0 + p * 64 + wc * 16 + lr;
#pragma unroll
          for (int r = 0; r < 4; ++r) Cout[(row + r) * Nsz + col] = acc[m][p][r];
        }
      }
    }
  } else {
    const int ntile = (int)(n0 >> 8);  // 0..17
#pragma unroll
    for (int m = 0; m < 2 * MH; ++m) {
      size_t row = m0 + wr * (BM / 2) + m * 16 + lh * 4;
      if (row >= 2048) continue;
#pragma unroll
      for (int p = 0; p < 4; ++p) {
        int col = (int)n0 + p * 64 + wc * 16 + lr;
        if (ntile < 14) {  // Q
          int hh = col >> 7, d = col & 127;
          float bias = qb[col];
#pragma unroll
          for (int r = 0; r < 4; ++r)
            Qo[((size_t)hh * S_N + row + r) * D_N + d] = f2bf(acc[m][p][r] + bias);
        } else if (ntile < 16) {  // K (unroped, unswizzled — k_rope finishes)
          int cc = col - E_N, kvh = cc >> 7, d = cc & 127;
          float bias = kb[cc];
#pragma unroll
          for (int r = 0; r < 4; ++r)
            Ko[((size_t)kvh * S_N + row + r) * D_N + d] = f2bf(acc[m][p][r] + bias);
        } else {  // V -> transposed [cc][s], within-64 swizzle; 4-run contiguous in s
          int cc = col - 4096;
          float bias = vb[cc];
          int s = (int)row;
          int pos = (s & ~63) | ((s & 63) ^ ((cc & 7) << 3));
          u16x4 vv;
#pragma unroll
          for (int r = 0; r < 4; ++r) vv[r] = f2bf(acc[m][p][r] + bias);
          *(u16x4*)(Vo + (size_t)cc * S_N + pos) = vv;
        }
      }
    }
  }
}

// ---------------- RoPE in-place on bf16 Q and K; K additionally swizzled ----------------
__global__ __launch_bounds__(256) void k_rope(u16* __restrict__ Qb, u16* __restrict__ Kb,
                                              const float* __restrict__ cosb,
                                              const float* __restrict__ sinb) {
  int s = blockIdx.x;
  int w = threadIdx.x >> 6, lane = threadIdx.x & 63;
  int head = blockIdx.y * 4 + w;  // 0..31
  float c0 = cosb[s * D_N + lane], c1 = cosb[s * D_N + lane + 64];
  float s0 = sinb[s * D_N + lane], s1 = sinb[s * D_N + lane + 64];
  if (head < H_N) {
    u16* p = Qb + ((size_t)head * S_N + s) * D_N;
    float x0 = bf2f(p[lane]), x1 = bf2f(p[lane + 64]);
    p[lane] = f2bf(x0 * c0 - x1 * s0);
    p[lane + 64] = f2bf(x1 * c1 + x0 * s1);
  } else {
    int kvh = head - H_N;
    u16* p = Kb + ((size_t)kvh * S_N + s) * D_N;
    float x0 = bf2f(p[lane]), x1 = bf2f(p[lane + 64]);
    float y0 = x0 * c0 - x1 * s0;
    float y1 = x1 * c1 + x0 * s1;
    int sw = (s & 15) << 3;
    p[lane ^ sw] = f2bf(y0);
    p[(lane + 64) ^ sw] = f2bf(y1);
  }
}

// ---------------- flash attention, GQA, causal ----------------
__global__ __launch_bounds__(256, 2) void k_attn(const u16* __restrict__ Q,
                                                 const u16* __restrict__ Kc,
                                                 const u16* __restrict__ Vt,
                                                 u16* __restrict__ Aout) {
  __shared__ __align__(16) u16 Klds[2][64 * 128];
  __shared__ __align__(16) u16 Vlds[2][128 * 64];
  const int h = blockIdx.y;
  const int kvh = h / 7;  // H/KVH = 7
  const int qt = (15 - blockIdx.x + ((blockIdx.y & 16) ? 8 : 0)) & 15;
  const int q0 = qt * 128;
  const int tid = threadIdx.x, w = tid >> 6, lane = tid & 63;
  const int l31 = lane & 31, hi = lane >> 5;
  const int hi8 = hi * 8;
  const int swK = (l31 & 15) << 3;  // K-read swizzle
  const int swV = (l31 & 7) << 3;   // V-read swizzle
  const int qloc = w * 32 + l31;
  const int qrow = q0 + qloc;

  bf16x8 qf[8];
  {
    const u16* qp = Q + ((size_t)h * S_N + qrow) * D_N + hi8;
#pragma unroll
    for (int dstep = 0; dstep < 8; ++dstep) qf[dstep] = *(const bf16x8*)(qp + dstep * 16);
  }

  f32x16 o[4];
#pragma unroll
  for (int i = 0; i < 4; i++)
#pragma unroll
    for (int r = 0; r < 16; r++) o[i][r] = 0.f;

  float m2 = -3.0e38f;
  float lsum = 0.f;
  const float msc = 0.12751743f;  // 1/sqrt(128) * log2(e)

  auto stageKV = [&](int buf, int t) {
    const u16* ks = Kc + ((size_t)kvh * S_N + t * 64) * D_N;
#pragma unroll
    for (int j = 0; j < 4; ++j)
      gload16(ks + (j * 256 + tid) * 8, &Klds[buf][(j * 256 + tid) * 8]);
    const u16* vs = Vt + (size_t)kvh * D_N * S_N + t * 64;
#pragma unroll
    for (int j = 0; j < 4; ++j) {
      int idx = j * 256 + tid;
      int dd = idx >> 3, cw = idx & 7;
      gload16(vs + (size_t)dd * S_N + cw * 8, &Vlds[buf][idx * 8]);
    }
  };

  const int nt = 2 * qt + 2;
  stageKV(0, 0);
  for (int t = 0; t < nt; ++t) {
    const int cur = t & 1;
    if (t + 1 < nt) {
      stageKV(cur ^ 1, t + 1);
      asm volatile("s_waitcnt vmcnt(8)" ::: "memory");  // tile t resident (FIFO)
    } else {
      asm volatile("s_waitcnt vmcnt(0)" ::: "memory");
    }
    SB0; BARR; SB0;
    f32x16 sacc[2];
#pragma unroll
    for (int i = 0; i < 2; i++)
#pragma unroll
      for (int r = 0; r < 16; r++) sacc[i][r] = 0.f;
    __builtin_amdgcn_s_setprio(1);
#pragma unroll
    for (int dstep = 0; dstep < 8; ++dstep)
#pragma unroll
      for (int ksub = 0; ksub < 2; ++ksub) {
        bf16x8 ka =
            *(const bf16x8*)&Klds[cur][(ksub * 32 + l31) * D_N + ((dstep * 16 + hi8) ^ swK)];
        sacc[ksub] = __builtin_amdgcn_mfma_f32_32x32x16_bf16(ka, qf[dstep], sacc[ksub], 0, 0, 0);
      }
    __builtin_amdgcn_s_setprio(0);
    if (t >= nt - 2) {
#pragma unroll
      for (int ksub = 0; ksub < 2; ++ksub)
#pragma unroll
        for (int r = 0; r < 16; ++r) {
          int kvg = t * 64 + ksub * 32 + (r & 3) + 8 * (r >> 2) + 4 * hi;
          sacc[ksub][r] = (kvg <= qrow) ? sacc[ksub][r] * msc : -3.0e38f;
        }
    } else {
#pragma unroll
      for (int ksub = 0; ksub < 2; ++ksub)
#pragma unroll
        for (int r = 0; r < 16; ++r) sacc[ksub][r] *= msc;
    }
    float tmax = fmaxf(vmax16(sacc[0]), vmax16(sacc[1]));
    tmax = fmaxf(tmax, __shfl_xor(tmax, 32));
    if (__any(tmax > m2 + 8.0f)) {
      float m2new = fmaxf(m2, tmax);
      float scl = __builtin_amdgcn_exp2f(m2 - m2new);
#pragma unroll
      for (int i = 0; i < 4; i++)
#pragma unroll
        for (int r = 0; r < 16; r++) o[i][r] *= scl;
      lsum *= scl;
      m2 = m2new;
    }
#pragma unroll
    for (int ksub = 0; ksub < 2; ++ksub) {
#pragma unroll
      for (int r = 0; r < 16; ++r)
        sacc[ksub][r] = __builtin_amdgcn_exp2f(sacc[ksub][r] - m2);
      lsum += vsum16(sacc[ksub]);
    }
    __builtin_amdgcn_s_setprio(1);
#pragma unroll
    for (int ksub = 0; ksub < 2; ++ksub) {
      u32 pw[8];
#pragma unroll
      for (int i = 0; i < 8; ++i) pw[i] = cvt_pk_bf16(sacc[ksub][2 * i], sacc[ksub][2 * i + 1]);
      pl32swap(pw[0], pw[2]);
      pl32swap(pw[1], pw[3]);
      pl32swap(pw[4], pw[6]);
      pl32swap(pw[5], pw[7]);
#pragma unroll
      for (int j = 0; j < 2; ++j) {
        u32x4 fw = {pw[j * 4 + 0], pw[j * 4 + 1], pw[j * 4 + 2], pw[j * 4 + 3]};
        bf16x8 pb = __builtin_bit_cast(bf16x8, fw);
#pragma unroll
        for (int dsub = 0; dsub < 4; ++dsub) {
          bf16x8 va = *(const bf16x8*)&Vlds[cur][(dsub * 32 + l31) * 64 +
                                                 ((ksub * 32 + j * 16 + hi8) ^ swV)];
          o[dsub] = __builtin_amdgcn_mfma_f32_32x32x16_bf16(va, pb, o[dsub], 0, 0, 0);
        }
      }
    }
    __builtin_amdgcn_s_setprio(0);
    SB0; BARR; SB0;
  }
  float lt = lsum + __shfl_xor(lsum, 32);
  float ri = 1.0f / lt;
  u16* op = Aout + (size_t)qrow * E_N + h * D_N;
  const int sw2 = (qrow & 7) << 3;  // GEMM-A pre-swizzle
#pragma unroll
  for (int dsub = 0; dsub < 4; ++dsub)
#pragma unroll
    for (int g = 0; g < 4; ++g) {
      int dbase = dsub * 32 + 8 * g + 4 * hi;
      u32x2 wv;
      wv[0] = (u32)f2bf(o[dsub][g * 4 + 0] * ri) | ((u32)f2bf(o[dsub][g * 4 + 1] * ri) << 16);
      wv[1] = (u32)f2bf(o[dsub][g * 4 + 2] * ri) | ((u32)f2bf(o[dsub][g * 4 + 3] * ri) << 16);
      *(u32x2*)(op + (dbase ^ sw2)) = wv;
    }
}

extern "C" void kernel_launch(void* const* d_in, const int* in_sizes, int n_in,
                              void* d_out, int out_size, void* d_ws, size_t ws_size,
                              hipStream_t stream) {
  const float* hs   = (const float*)d_in[0];
  const float* cosb = (const float*)d_in[1];
  const float* sinb = (const float*)d_in[2];
  // d_in[3] = attn_mask (causal tril — applied analytically)
  const float* qw = (const float*)d_in[4];
  const float* qb = (const float*)d_in[5];
  const float* kw = (const float*)d_in[6];
  const float* kb = (const float*)d_in[7];
  const float* vw = (const float*)d_in[8];
  const float* vb = (const float*)d_in[9];
  const float* ow = (const float*)d_in[10];
  float* outp = (float*)d_out;

  char* ws = (char*)d_ws;
  u16* hsb    = (u16*)(ws);                       // 2048x3584 bf16 (swz)           14.7MB
  u16* wt     = (u16*)(ws + 14680064);            // 4608x3584 bf16 (swz; later ow^T) 33MB
  u16* attn_o = (u16*)(ws + 47710208);            // 2048x3584 bf16 (swz)           14.7MB
  u16* Qb     = (u16*)(ws + 62390272);            // [28][2048][128]                14.7MB
  u16* Kb     = (u16*)(ws + 77070336);            // [4][2048][128] (swz after rope)  2MB
  u16* Vtb    = (u16*)(ws + 79167488);            // [512][2048] (swz within-64)      2MB

  // 1. hs -> bf16 (GEMM-swizzled)
  k_hs_bf16_swz<<<dim3(917504 / 256), dim3(256), 0, stream>>>(hs, hsb);
  // 2-4. weight transposes -> wt (q|k|v rows, GEMM-swizzled)
  k_transpose_bf16<<<dim3(3584 / 64, 3584 / 64), dim3(256), 0, stream>>>(qw, wt, 3584, 3584);
  k_transpose_bf16<<<dim3(512 / 64, 3584 / 64), dim3(256), 0, stream>>>(kw, wt + (size_t)3584 * 3584, 3584, 512);
  k_transpose_bf16<<<dim3(512 / 64, 3584 / 64), dim3(256), 0, stream>>>(vw, wt + (size_t)4096 * 3584, 3584, 512);
  // 5. QKV GEMM with fused bias+layout epilogue (198 blocks)
  k_gemm<192, 1><<<dim3(198), dim3(512), 0, stream>>>(hsb, wt, nullptr, 4608, 18,
                                                      qb, kb, vb, Qb, Kb, Vtb);
  // 6. RoPE in-place (Q plain, K swizzled)
  k_rope<<<dim3(2048, 8), dim3(256), 0, stream>>>(Qb, Kb, cosb, sinb);
  // 7. ow transpose (into wt region — gemm1 already consumed it)
  k_transpose_bf16<<<dim3(3584 / 64, 3584 / 64), dim3(256), 0, stream>>>(ow, wt, 3584, 3584);
  // 8. attention -> attn_o (bf16, GEMM-swizzled)
  k_attn<<<dim3(16, 28), dim3(256), 0, stream>>>(Qb, Kb, Vtb, attn_o);
  // 9. output projection (224 blocks, full CU fill)
  k_gemm<128, 0><<<dim3(224), dim3(512), 0, stream>>>(attn_o, wt, outp, 3584, 14,
                                                      nullptr, nullptr, nullptr,
                                                      nullptr, nullptr, nullptr);
}

// Round 11
// 254.736 us; speedup vs baseline: 1.0803x; 1.0803x over previous
//
#include <hip/hip_runtime.h>

#define H_N 28
#define KVH_N 4
#define D_N 128
#define S_N 2048
#define E_N 3584
#define NQKV 4608

typedef unsigned short u16;
typedef unsigned int u32;
typedef __bf16 bf16x8 __attribute__((ext_vector_type(8)));
typedef float f32x4 __attribute__((ext_vector_type(4)));
typedef float f32x16 __attribute__((ext_vector_type(16)));
typedef unsigned short u16x4 __attribute__((ext_vector_type(4)));
typedef unsigned short u16x8 __attribute__((ext_vector_type(8)));
typedef unsigned int u32x2 __attribute__((ext_vector_type(2)));
typedef unsigned int u32x4 __attribute__((ext_vector_type(4)));

typedef __attribute__((address_space(1))) void gvoid_t;
typedef __attribute__((address_space(3))) void lvoid_t;

static __device__ __forceinline__ u16 f2bf(float f) {
  __bf16 h = (__bf16)f;
  return __builtin_bit_cast(unsigned short, h);
}

static __device__ __forceinline__ float bf2f(u16 b) {
  u32 u = (u32)b << 16;
  return __builtin_bit_cast(float, u);
}

static __device__ __forceinline__ void gload16(const void* g, void* l) {
  __builtin_amdgcn_global_load_lds((gvoid_t*)g, (lvoid_t*)l, 16, 0, 0);
}

static __device__ __forceinline__ u32 cvt_pk_bf16(float lo, float hi) {
  u32 r;
  asm("v_cvt_pk_bf16_f32 %0, %1, %2" : "=v"(r) : "v"(lo), "v"(hi));
  return r;
}

static __device__ __forceinline__ void pl32swap(u32& a, u32& b) {
  asm volatile("v_permlane32_swap_b32 %0, %1" : "+v"(a), "+v"(b));
}

static __device__ __forceinline__ float vmax16(f32x16 v) {
  float a = fmaxf(fmaxf(v[0], v[1]), fmaxf(v[2], v[3]));
  float b = fmaxf(fmaxf(v[4], v[5]), fmaxf(v[6], v[7]));
  float c = fmaxf(fmaxf(v[8], v[9]), fmaxf(v[10], v[11]));
  float d = fmaxf(fmaxf(v[12], v[13]), fmaxf(v[14], v[15]));
  return fmaxf(fmaxf(a, b), fmaxf(c, d));
}

static __device__ __forceinline__ float vsum16(f32x16 v) {
  float a = (v[0] + v[1]) + (v[2] + v[3]);
  float b = (v[4] + v[5]) + (v[6] + v[7]);
  float c = (v[8] + v[9]) + (v[10] + v[11]);
  float d = (v[12] + v[13]) + (v[14] + v[15]);
  return (a + b) + (c + d);
}

// ---------------- hs f32 -> bf16, GEMM-swizzled (8-elem group ^= row&7) ----------------
__global__ __launch_bounds__(256) void k_hs_bf16_swz(const float* __restrict__ in,
                                                     u16* __restrict__ out) {
  int g = blockIdx.x * 256 + threadIdx.x;  // 2048*3584/8 groups
  int row = g / 448, c8 = g % 448;
  const float4* p = (const float4*)(in + (size_t)g * 8);
  float4 a = p[0], b = p[1];
  u16x8 r;
  r[0] = f2bf(a.x); r[1] = f2bf(a.y); r[2] = f2bf(a.z); r[3] = f2bf(a.w);
  r[4] = f2bf(b.x); r[5] = f2bf(b.y); r[6] = f2bf(b.z); r[7] = f2bf(b.w);
  int dc8 = c8 ^ (row & 7);
  *(u16x8*)(out + (size_t)row * E_N + dc8 * 8) = r;
}

// ---------------- transpose f32 [R][C] -> bf16 [C][R], GEMM-swizzled rows ----------------
__global__ __launch_bounds__(256) void k_transpose_bf16(const float* __restrict__ in,
                                                        u16* __restrict__ out,
                                                        int R, int C) {
  __shared__ float t[64][65];
  int r0 = blockIdx.y * 64, c0 = blockIdx.x * 64;
  int lr = threadIdx.x >> 6, lc = threadIdx.x & 63;
#pragma unroll
  for (int i = 0; i < 64; i += 4)
    t[lr + i][lc] = in[(size_t)(r0 + lr + i) * C + c0 + lc];
  __syncthreads();
#pragma unroll
  for (int i = 0; i < 64; i += 4) {
    int orow = c0 + lr + i;
    int sw = (orow & 7) << 3;
    out[(size_t)orow * R + r0 + (lc ^ sw)] = f2bf(t[lc][lr + i]);
  }
}

// -------- merged qw/kw/vw transpose: one launch, bx selects source segment ----------
__global__ __launch_bounds__(256) void k_wtrans(const float* __restrict__ qw,
                                                const float* __restrict__ kw,
                                                const float* __restrict__ vw,
                                                u16* __restrict__ wt) {
  __shared__ float t[64][65];
  int bx = blockIdx.x;
  const float* in;
  u16* out;
  int C, c0;
  if (bx < 56) {
    in = qw; out = wt; C = 3584; c0 = bx * 64;
  } else if (bx < 64) {
    in = kw; out = wt + (size_t)3584 * 3584; C = 512; c0 = (bx - 56) * 64;
  } else {
    in = vw; out = wt + (size_t)4096 * 3584; C = 512; c0 = (bx - 64) * 64;
  }
  int r0 = blockIdx.y * 64;
  int lr = threadIdx.x >> 6, lc = threadIdx.x & 63;
#pragma unroll
  for (int i = 0; i < 64; i += 4)
    t[lr + i][lc] = in[(size_t)(r0 + lr + i) * C + c0 + lc];
  __syncthreads();
#pragma unroll
  for (int i = 0; i < 64; i += 4) {
    int orow = c0 + lr + i;
    int sw = (orow & 7) << 3;
    out[(size_t)orow * 3584 + r0 + (lc ^ sw)] = f2bf(t[lc][lr + i]);
  }
}

// =================== GEMM BMx256, BK=64, 8 waves, balanced 4-phase (round-9) ===========
// Phases (12 MFMA each): P0 rdA-halfA+B q01; P1 rdA-halfB; P2 rdB q23; P3 none.
// Stage: P0:(T+1).B2,B3->buf^1  P1:(T+2).B0,B1  P2:(T+2).A0,A1  P3:(T+2).A2 (NA==3)
// vmcnt(UNITS-2) at P3 -> tile T+1 fully resident. EPI=1: fused QKV epilogue.
#define BARR __builtin_amdgcn_s_barrier()
#define SB0 __builtin_amdgcn_sched_barrier(0)
#define LGKM0 asm volatile("s_waitcnt lgkmcnt(0)" ::: "memory")
#define VMW5 asm volatile("s_waitcnt vmcnt(5)" ::: "memory")
#define VMW4 asm volatile("s_waitcnt vmcnt(4)" ::: "memory")
#define VMW0 asm volatile("s_waitcnt vmcnt(0)" ::: "memory")

template <int BM, int EPI>
__global__ __launch_bounds__(512, 2) void k_gemm(const u16* __restrict__ A,
                                                 const u16* __restrict__ Bt,
                                                 float* __restrict__ Cout,
                                                 int Nn, int nxt,
                                                 const float* __restrict__ qb,
                                                 const float* __restrict__ kb,
                                                 const float* __restrict__ vb,
                                                 u16* __restrict__ Qo,
                                                 u16* __restrict__ Ko,
                                                 u16* __restrict__ Vo) {
  constexpr int NA = BM / 64;   // A stage units (3 or 2)
  constexpr int MH = NA;        // m-frags per half per wave
  constexpr int UNITS = NA + 4;
  constexpr int LROWS = BM + 256;
  __shared__ __align__(16) u16 L[2 * LROWS * 64];
  const int K = 3584, NKT = 56;
  const int tid = threadIdx.x;
  const int lane = tid & 63;
  const int w = tid >> 6;
  const int lr = lane & 15, lh = lane >> 4, lh8 = lh * 8;
  const int swz = (lr & 7) << 3;
  const int wr = w >> 2, wc = w & 3;  // 2 M-waves x 4 N-waves

  // bijective XCD swizzle (m204)
  const int nwg = gridDim.x;
  const int bid = blockIdx.x;
  const int q8 = nwg >> 3, r8 = nwg & 7;
  const int xcd = bid & 7, idx = bid >> 3;
  const int lb = (xcd < r8 ? xcd * (q8 + 1) : r8 * (q8 + 1) + (xcd - r8) * q8) + idx;
  const size_t m0 = (size_t)(lb / nxt) * BM;
  const size_t n0 = (size_t)(lb % nxt) << 8;

  const u16* __restrict__ Ab = A + m0 * K;
  const u16* __restrict__ Bb = Bt + n0 * K;

  const int srow = tid >> 3, scol8 = tid & 7;
  auto stg = [&](int buf, int u, int kt) {
    if (kt >= NKT) return;
    const u16* src;
    int ldsrow;
    if (u < NA) {
      src = Ab + (size_t)(u * 64 + srow) * K;
      ldsrow = u * 64 + srow;
    } else {
      src = Bb + (size_t)((u - NA) * 64 + srow) * K;
      ldsrow = BM + (u - NA) * 64 + srow;
    }
    gload16(src + kt * 64 + scol8 * 8, &L[buf * (LROWS * 64) + ldsrow * 64 + scol8 * 8]);
  };

  f32x4 acc[2 * MH][4];
#pragma unroll
  for (int i = 0; i < 2 * MH; i++)
#pragma unroll
    for (int j = 0; j < 4; j++) acc[i][j] = f32x4{0.f, 0.f, 0.f, 0.f};

  bf16x8 afA[MH][2], afB[MH][2], bq[2][2];

  auto rdA = [&](bf16x8(&arr)[MH][2], int LB, int mbase) {
#pragma unroll
    for (int mm = 0; mm < MH; ++mm)
#pragma unroll
      for (int kk = 0; kk < 2; ++kk)
        arr[mm][kk] = *(const bf16x8*)&L[LB + (wr * (BM / 2) + (mbase + mm) * 16 + lr) * 64 +
                                         ((kk * 32 + lh8) ^ swz)];
  };
  auto rdB = [&](int LB, int qbase) {
#pragma unroll
    for (int j = 0; j < 2; ++j)
#pragma unroll
      for (int kk = 0; kk < 2; ++kk)
        bq[j][kk] = *(const bf16x8*)&L[LB + (BM + (qbase + j) * 64 + wc * 16 + lr) * 64 +
                                       ((kk * 32 + lh8) ^ swz)];
  };
  auto mm4 = [&](bf16x8(&af)[MH][2], int mbase, int qbase) {
    __builtin_amdgcn_s_setprio(1);
#pragma unroll
    for (int mm = 0; mm < MH; ++mm)
#pragma unroll
      for (int j = 0; j < 2; ++j)
#pragma unroll
        for (int kk = 0; kk < 2; ++kk)
          acc[mbase + mm][qbase + j] = __builtin_amdgcn_mfma_f32_16x16x32_bf16(
              af[mm][kk], bq[j][kk], acc[mbase + mm][qbase + j], 0, 0, 0);
    __builtin_amdgcn_s_setprio(0);
  };

  // prologue: tile0 all units; tile1 {B0,B1,A0,A1,(A2)}; drain tile0.
#pragma unroll
  for (int u = 0; u < UNITS; ++u) stg(0, u, 0);
  stg(1, NA + 0, 1); stg(1, NA + 1, 1); stg(1, 0, 1); stg(1, 1, 1);
  if constexpr (NA == 3) stg(1, 2, 1);
  if constexpr (UNITS == 7) { VMW5; } else { VMW4; }
  BARR;

  for (int T = 0; T < NKT; ++T) {
    const int cur = T & 1;
    const int LB = cur * (LROWS * 64);
    // P0
    rdA(afA, LB, 0);
    rdB(LB, 0);
    stg(cur ^ 1, NA + 2, T + 1);
    stg(cur ^ 1, NA + 3, T + 1);
    BARR; LGKM0;
    mm4(afA, 0, 0);
    BARR;
    // P1
    rdA(afB, LB, MH);
    stg(cur, NA + 0, T + 2);
    stg(cur, NA + 1, T + 2);
    BARR; LGKM0;
    mm4(afB, MH, 0);
    BARR;
    // P2
    rdB(LB, 2);
    stg(cur, 0, T + 2);
    stg(cur, 1, T + 2);
    BARR; LGKM0;
    mm4(afA, 0, 2);
    BARR;
    // P3
    if constexpr (NA == 3) stg(cur, 2, T + 2);
    if (T + 2 < NKT) {
      if constexpr (UNITS == 7) { VMW5; } else { VMW4; }
    } else {
      VMW0;
    }
    BARR;
    mm4(afB, MH, 2);
    BARR;
  }

  if constexpr (EPI == 0) {
    const size_t Nsz = (size_t)Nn;
#pragma unroll
    for (int m = 0; m < 2 * MH; ++m) {
      size_t row = m0 + wr * (BM / 2) + m * 16 + lh * 4;
      if (row < 2048) {
#pragma unroll
        for (int p = 0; p < 4; ++p) {
          size_t col = n0 + p * 64 + wc * 16 + lr;
#pragma unroll
          for (int r = 0; r < 4; ++r) Cout[(row + r) * Nsz + col] = acc[m][p][r];
        }
      }
    }
  } else {
    const int ntile = (int)(n0 >> 8);  // 0..17
#pragma unroll
    for (int m = 0; m < 2 * MH; ++m) {
      size_t row = m0 + wr * (BM / 2) + m * 16 + lh * 4;
      if (row >= 2048) continue;
#pragma unroll
      for (int p = 0; p < 4; ++p) {
        int col = (int)n0 + p * 64 + wc * 16 + lr;
        if (ntile < 14) {  // Q (unroped — attn ropes in-register)
          int hh = col >> 7, d = col & 127;
          float bias = qb[col];
#pragma unroll
          for (int r = 0; r < 4; ++r)
            Qo[((size_t)hh * S_N + row + r) * D_N + d] = f2bf(acc[m][p][r] + bias);
        } else if (ntile < 16) {  // K (unroped, unswizzled — k_ropek finishes)
          int cc = col - E_N, kvh = cc >> 7, d = cc & 127;
          float bias = kb[cc];
#pragma unroll
          for (int r = 0; r < 4; ++r)
            Ko[((size_t)kvh * S_N + row + r) * D_N + d] = f2bf(acc[m][p][r] + bias);
        } else {  // V -> transposed [cc][s], within-64 swizzle; 4-run contiguous in s
          int cc = col - 4096;
          float bias = vb[cc];
          int s = (int)row;
          int pos = (s & ~63) | ((s & 63) ^ ((cc & 7) << 3));
          u16x4 vv;
#pragma unroll
          for (int r = 0; r < 4; ++r) vv[r] = f2bf(acc[m][p][r] + bias);
          *(u16x4*)(Vo + (size_t)cc * S_N + pos) = vv;
        }
      }
    }
  }
}

// ---------------- RoPE in-place on bf16 K only; writes swizzled ----------------
// One wave per (kvh, s) row; wave-lockstep makes the in-place permutation race-free.
__global__ __launch_bounds__(256) void k_ropek(u16* __restrict__ Kb,
                                               const float* __restrict__ cosb,
                                               const float* __restrict__ sinb) {
  int s = blockIdx.x;
  int kvh = threadIdx.x >> 6, lane = threadIdx.x & 63;
  float c0 = cosb[s * D_N + lane], c1 = cosb[s * D_N + lane + 64];
  float s0 = sinb[s * D_N + lane], s1 = sinb[s * D_N + lane + 64];
  u16* p = Kb + ((size_t)kvh * S_N + s) * D_N;
  float x0 = bf2f(p[lane]), x1 = bf2f(p[lane + 64]);
  float y0 = x0 * c0 - x1 * s0;
  float y1 = x1 * c1 + x0 * s1;
  int sw = (s & 15) << 3;
  p[lane ^ sw] = f2bf(y0);
  p[(lane + 64) ^ sw] = f2bf(y1);
}

// ---------------- flash attention, GQA, causal; Q-RoPE fused in prologue ----------------
__global__ __launch_bounds__(256, 2) void k_attn(const u16* __restrict__ Q,
                                                 const u16* __restrict__ Kc,
                                                 const u16* __restrict__ Vt,
                                                 const float* __restrict__ cosb,
                                                 const float* __restrict__ sinb,
                                                 u16* __restrict__ Aout) {
  __shared__ __align__(16) u16 Klds[2][64 * 128];
  __shared__ __align__(16) u16 Vlds[2][128 * 64];
  const int h = blockIdx.y;
  const int kvh = h / 7;  // H/KVH = 7
  const int qt = (15 - blockIdx.x + ((blockIdx.y & 16) ? 8 : 0)) & 15;
  const int q0 = qt * 128;
  const int tid = threadIdx.x, w = tid >> 6, lane = tid & 63;
  const int l31 = lane & 31, hi = lane >> 5;
  const int hi8 = hi * 8;
  const int swK = (l31 & 15) << 3;  // K-read swizzle
  const int swV = (l31 & 7) << 3;   // V-read swizzle
  const int qloc = w * 32 + l31;
  const int qrow = q0 + qloc;

  // Q fragments with in-register RoPE: frag f (d<64) pairs with f+4 (d+64).
  bf16x8 qf[8];
  {
    const u16* qp = Q + ((size_t)h * S_N + qrow) * D_N + hi8;
    const float* cb = cosb + (size_t)qrow * D_N + hi8;
    const float* sb = sinb + (size_t)qrow * D_N + hi8;
#pragma unroll
    for (int f = 0; f < 4; ++f) {
      u16x8 ulo = __builtin_bit_cast(u16x8, *(const bf16x8*)(qp + f * 16));
      u16x8 uhi = __builtin_bit_cast(u16x8, *(const bf16x8*)(qp + (f + 4) * 16));
      u16x8 olo, ohi;
#pragma unroll
      for (int e = 0; e < 8; ++e) {
        float xl = bf2f(ulo[e]), xh = bf2f(uhi[e]);
        float cl = cb[f * 16 + e], sl = sb[f * 16 + e];
        float ch = cb[(f + 4) * 16 + e], sh = sb[(f + 4) * 16 + e];
        olo[e] = f2bf(xl * cl - xh * sl);
        ohi[e] = f2bf(xh * ch + xl * sh);
      }
      qf[f] = __builtin_bit_cast(bf16x8, olo);
      qf[f + 4] = __builtin_bit_cast(bf16x8, ohi);
    }
  }

  f32x16 o[4];
#pragma unroll
  for (int i = 0; i < 4; i++)
#pragma unroll
    for (int r = 0; r < 16; r++) o[i][r] = 0.f;

  float m2 = -3.0e38f;
  float lsum = 0.f;
  const float msc = 0.12751743f;  // 1/sqrt(128) * log2(e)

  auto stageKV = [&](int buf, int t) {
    const u16* ks = Kc + ((size_t)kvh * S_N + t * 64) * D_N;
#pragma unroll
    for (int j = 0; j < 4; ++j)
      gload16(ks + (j * 256 + tid) * 8, &Klds[buf][(j * 256 + tid) * 8]);
    const u16* vs = Vt + (size_t)kvh * D_N * S_N + t * 64;
#pragma unroll
    for (int j = 0; j < 4; ++j) {
      int idx = j * 256 + tid;
      int dd = idx >> 3, cw = idx & 7;
      gload16(vs + (size_t)dd * S_N + cw * 8, &Vlds[buf][idx * 8]);
    }
  };

  const int nt = 2 * qt + 2;
  stageKV(0, 0);
  for (int t = 0; t < nt; ++t) {
    const int cur = t & 1;
    if (t + 1 < nt) {
      stageKV(cur ^ 1, t + 1);
      asm volatile("s_waitcnt vmcnt(8)" ::: "memory");  // tile t resident (FIFO)
    } else {
      asm volatile("s_waitcnt vmcnt(0)" ::: "memory");
    }
    SB0; BARR; SB0;
    f32x16 sacc[2];
#pragma unroll
    for (int i = 0; i < 2; i++)
#pragma unroll
      for (int r = 0; r < 16; r++) sacc[i][r] = 0.f;
    __builtin_amdgcn_s_setprio(1);
#pragma unroll
    for (int dstep = 0; dstep < 8; ++dstep)
#pragma unroll
      for (int ksub = 0; ksub < 2; ++ksub) {
        bf16x8 ka =
            *(const bf16x8*)&Klds[cur][(ksub * 32 + l31) * D_N + ((dstep * 16 + hi8) ^ swK)];
        sacc[ksub] = __builtin_amdgcn_mfma_f32_32x32x16_bf16(ka, qf[dstep], sacc[ksub], 0, 0, 0);
      }
    __builtin_amdgcn_s_setprio(0);
    if (t >= nt - 2) {
#pragma unroll
      for (int ksub = 0; ksub < 2; ++ksub)
#pragma unroll
        for (int r = 0; r < 16; ++r) {
          int kvg = t * 64 + ksub * 32 + (r & 3) + 8 * (r >> 2) + 4 * hi;
          sacc[ksub][r] = (kvg <= qrow) ? sacc[ksub][r] * msc : -3.0e38f;
        }
    } else {
#pragma unroll
      for (int ksub = 0; ksub < 2; ++ksub)
#pragma unroll
        for (int r = 0; r < 16; ++r) sacc[ksub][r] *= msc;
    }
    float tmax = fmaxf(vmax16(sacc[0]), vmax16(sacc[1]));
    tmax = fmaxf(tmax, __shfl_xor(tmax, 32));
    if (__any(tmax > m2 + 8.0f)) {
      float m2new = fmaxf(m2, tmax);
      float scl = __builtin_amdgcn_exp2f(m2 - m2new);
#pragma unroll
      for (int i = 0; i < 4; i++)
#pragma unroll
        for (int r = 0; r < 16; r++) o[i][r] *= scl;
      lsum *= scl;
      m2 = m2new;
    }
#pragma unroll
    for (int ksub = 0; ksub < 2; ++ksub) {
#pragma unroll
      for (int r = 0; r < 16; ++r)
        sacc[ksub][r] = __builtin_amdgcn_exp2f(sacc[ksub][r] - m2);
      lsum += vsum16(sacc[ksub]);
    }
    __builtin_amdgcn_s_setprio(1);
#pragma unroll
    for (int ksub = 0; ksub < 2; ++ksub) {
      u32 pw[8];
#pragma unroll
      for (int i = 0; i < 8; ++i) pw[i] = cvt_pk_bf16(sacc[ksub][2 * i], sacc[ksub][2 * i + 1]);
      pl32swap(pw[0], pw[2]);
      pl32swap(pw[1], pw[3]);
      pl32swap(pw[4], pw[6]);
      pl32swap(pw[5], pw[7]);
#pragma unroll
      for (int j = 0; j < 2; ++j) {
        u32x4 fw = {pw[j * 4 + 0], pw[j * 4 + 1], pw[j * 4 + 2], pw[j * 4 + 3]};
        bf16x8 pb = __builtin_bit_cast(bf16x8, fw);
#pragma unroll
        for (int dsub = 0; dsub < 4; ++dsub) {
          bf16x8 va = *(const bf16x8*)&Vlds[cur][(dsub * 32 + l31) * 64 +
                                                 ((ksub * 32 + j * 16 + hi8) ^ swV)];
          o[dsub] = __builtin_amdgcn_mfma_f32_32x32x16_bf16(va, pb, o[dsub], 0, 0, 0);
        }
      }
    }
    __builtin_amdgcn_s_setprio(0);
    SB0; BARR; SB0;
  }
  float lt = lsum + __shfl_xor(lsum, 32);
  float ri = 1.0f / lt;
  u16* op = Aout + (size_t)qrow * E_N + h * D_N;
  const int sw2 = (qrow & 7) << 3;  // GEMM-A pre-swizzle
#pragma unroll
  for (int dsub = 0; dsub < 4; ++dsub)
#pragma unroll
    for (int g = 0; g < 4; ++g) {
      int dbase = dsub * 32 + 8 * g + 4 * hi;
      u32x2 wv;
      wv[0] = (u32)f2bf(o[dsub][g * 4 + 0] * ri) | ((u32)f2bf(o[dsub][g * 4 + 1] * ri) << 16);
      wv[1] = (u32)f2bf(o[dsub][g * 4 + 2] * ri) | ((u32)f2bf(o[dsub][g * 4 + 3] * ri) << 16);
      *(u32x2*)(op + (dbase ^ sw2)) = wv;
    }
}

extern "C" void kernel_launch(void* const* d_in, const int* in_sizes, int n_in,
                              void* d_out, int out_size, void* d_ws, size_t ws_size,
                              hipStream_t stream) {
  const float* hs   = (const float*)d_in[0];
  const float* cosb = (const float*)d_in[1];
  const float* sinb = (const float*)d_in[2];
  // d_in[3] = attn_mask (causal tril — applied analytically)
  const float* qw = (const float*)d_in[4];
  const float* qb = (const float*)d_in[5];
  const float* kw = (const float*)d_in[6];
  const float* kb = (const float*)d_in[7];
  const float* vw = (const float*)d_in[8];
  const float* vb = (const float*)d_in[9];
  const float* ow = (const float*)d_in[10];
  float* outp = (float*)d_out;

  char* ws = (char*)d_ws;
  u16* hsb    = (u16*)(ws);                       // 2048x3584 bf16 (swz)           14.7MB
  u16* wt     = (u16*)(ws + 14680064);            // 4608x3584 bf16 (swz; later ow^T) 33MB
  u16* attn_o = (u16*)(ws + 47710208);            // 2048x3584 bf16 (swz)           14.7MB
  u16* Qb     = (u16*)(ws + 62390272);            // [28][2048][128] (unroped)      14.7MB
  u16* Kb     = (u16*)(ws + 77070336);            // [4][2048][128] (swz after rope)  2MB
  u16* Vtb    = (u16*)(ws + 79167488);            // [512][2048] (swz within-64)      2MB

  // 1. hs -> bf16 (GEMM-swizzled)
  k_hs_bf16_swz<<<dim3(917504 / 256), dim3(256), 0, stream>>>(hs, hsb);
  // 2. merged qw/kw/vw transposes -> wt (GEMM-swizzled)
  k_wtrans<<<dim3(72, 56), dim3(256), 0, stream>>>(qw, kw, vw, wt);
  // 3. QKV GEMM with fused bias+layout epilogue (198 blocks)
  k_gemm<192, 1><<<dim3(198), dim3(512), 0, stream>>>(hsb, wt, nullptr, 4608, 18,
                                                      qb, kb, vb, Qb, Kb, Vtb);
  // 4. RoPE in-place on K (swizzled); Q roped in-register inside k_attn
  k_ropek<<<dim3(2048), dim3(256), 0, stream>>>(Kb, cosb, sinb);
  // 5. ow transpose (into wt region — QKV GEMM already consumed it)
  k_transpose_bf16<<<dim3(3584 / 64, 3584 / 64), dim3(256), 0, stream>>>(ow, wt, 3584, 3584);
  // 6. attention -> attn_o (bf16, GEMM-swizzled)
  k_attn<<<dim3(16, 28), dim3(256), 0, stream>>>(Qb, Kb, Vtb, cosb, sinb, attn_o);
  // 7. output projection (224 blocks, full CU fill)
  k_gemm<128, 0><<<dim3(224), dim3(512), 0, stream>>>(attn_o, wt, outp, 3584, 14,
                                                      nullptr, nullptr, nullptr,
                                                      nullptr, nullptr, nullptr);
}

// Round 12
// 248.665 us; speedup vs baseline: 1.1066x; 1.0244x over previous
//
#include <hip/hip_runtime.h>

#define H_N 28
#define KVH_N 4
#define D_N 128
#define S_N 2048
#define E_N 3584
#define NQKV 4608

typedef unsigned short u16;
typedef unsigned int u32;
typedef __bf16 bf16x8 __attribute__((ext_vector_type(8)));
typedef float f32x4 __attribute__((ext_vector_type(4)));
typedef float f32x16 __attribute__((ext_vector_type(16)));
typedef unsigned short u16x4 __attribute__((ext_vector_type(4)));
typedef unsigned short u16x8 __attribute__((ext_vector_type(8)));
typedef unsigned int u32x2 __attribute__((ext_vector_type(2)));
typedef unsigned int u32x4 __attribute__((ext_vector_type(4)));

typedef __attribute__((address_space(1))) void gvoid_t;
typedef __attribute__((address_space(3))) void lvoid_t;

static __device__ __forceinline__ u16 f2bf(float f) {
  __bf16 h = (__bf16)f;
  return __builtin_bit_cast(unsigned short, h);
}

static __device__ __forceinline__ float bf2f(u16 b) {
  u32 u = (u32)b << 16;
  return __builtin_bit_cast(float, u);
}

static __device__ __forceinline__ void gload16(const void* g, void* l) {
  __builtin_amdgcn_global_load_lds((gvoid_t*)g, (lvoid_t*)l, 16, 0, 0);
}

static __device__ __forceinline__ void gload4(const void* g, void* l) {
  __builtin_amdgcn_global_load_lds((gvoid_t*)g, (lvoid_t*)l, 4, 0, 0);
}

static __device__ __forceinline__ u32 cvt_pk_bf16(float lo, float hi) {
  u32 r;
  asm("v_cvt_pk_bf16_f32 %0, %1, %2" : "=v"(r) : "v"(lo), "v"(hi));
  return r;
}

static __device__ __forceinline__ void pl32swap(u32& a, u32& b) {
  asm volatile("v_permlane32_swap_b32 %0, %1" : "+v"(a), "+v"(b));
}

static __device__ __forceinline__ float vmax16(f32x16 v) {
  float a = fmaxf(fmaxf(v[0], v[1]), fmaxf(v[2], v[3]));
  float b = fmaxf(fmaxf(v[4], v[5]), fmaxf(v[6], v[7]));
  float c = fmaxf(fmaxf(v[8], v[9]), fmaxf(v[10], v[11]));
  float d = fmaxf(fmaxf(v[12], v[13]), fmaxf(v[14], v[15]));
  return fmaxf(fmaxf(a, b), fmaxf(c, d));
}

static __device__ __forceinline__ float vsum16(f32x16 v) {
  float a = (v[0] + v[1]) + (v[2] + v[3]);
  float b = (v[4] + v[5]) + (v[6] + v[7]);
  float c = (v[8] + v[9]) + (v[10] + v[11]);
  float d = (v[12] + v[13]) + (v[14] + v[15]);
  return (a + b) + (c + d);
}

// ---------------- hs f32 -> bf16, GEMM-swizzled (8-elem group ^= row&7) ----------------
__global__ __launch_bounds__(256) void k_hs_bf16_swz(const float* __restrict__ in,
                                                     u16* __restrict__ out) {
  int g = blockIdx.x * 256 + threadIdx.x;  // 2048*3584/8 groups
  int row = g / 448, c8 = g % 448;
  const float4* p = (const float4*)(in + (size_t)g * 8);
  float4 a = p[0], b = p[1];
  u16x8 r;
  r[0] = f2bf(a.x); r[1] = f2bf(a.y); r[2] = f2bf(a.z); r[3] = f2bf(a.w);
  r[4] = f2bf(b.x); r[5] = f2bf(b.y); r[6] = f2bf(b.z); r[7] = f2bf(b.w);
  int dc8 = c8 ^ (row & 7);
  *(u16x8*)(out + (size_t)row * E_N + dc8 * 8) = r;
}

// -------- merged qw/kw/vw/ow transpose: one launch, bx selects source segment ----------
__global__ __launch_bounds__(256) void k_wtrans(const float* __restrict__ qw,
                                                const float* __restrict__ kw,
                                                const float* __restrict__ vw,
                                                const float* __restrict__ ow,
                                                u16* __restrict__ wt,
                                                u16* __restrict__ wt2) {
  __shared__ float t[64][65];
  int bx = blockIdx.x;
  const float* in;
  u16* out;
  int C, c0;
  if (bx < 56) {
    in = qw; out = wt; C = 3584; c0 = bx * 64;
  } else if (bx < 64) {
    in = kw; out = wt + (size_t)3584 * 3584; C = 512; c0 = (bx - 56) * 64;
  } else if (bx < 72) {
    in = vw; out = wt + (size_t)4096 * 3584; C = 512; c0 = (bx - 64) * 64;
  } else {
    in = ow; out = wt2; C = 3584; c0 = (bx - 72) * 64;
  }
  int r0 = blockIdx.y * 64;
  int lr = threadIdx.x >> 6, lc = threadIdx.x & 63;
#pragma unroll
  for (int i = 0; i < 64; i += 4)
    t[lr + i][lc] = in[(size_t)(r0 + lr + i) * C + c0 + lc];
  __syncthreads();
#pragma unroll
  for (int i = 0; i < 64; i += 4) {
    int orow = c0 + lr + i;
    int sw = (orow & 7) << 3;
    out[(size_t)orow * 3584 + r0 + (lc ^ sw)] = f2bf(t[lc][lr + i]);
  }
}

// =================== GEMM BMx256, BK=64, 8 waves, balanced 4-phase =====================
// BM in {128, 160, 192}. A tail (BM=160): 32-row unit staged via 2x width-4
// global_load_lds (uniform per-wave issue count). Issues/tile: 6/8/7 -> counted
// vmcnt(ISS-2) at P3 keeps exactly tile T+1 resident (FIFO-traced).
// Phases (m-frags split MHA+MHB): P0 rdA-halfA+B q01; P1 rdA-halfB; P2 rdB q23; P3 none.
// Stage: P0:(T+1).B2,B3->buf^1  P1:(T+2).B0,B1  P2:(T+2).A0,A1  P3:(T+2).A2/tail
// EPI=1: fused QKV epilogue (Q/K unroped bf16; V transposed+swizzled).
#define BARR __builtin_amdgcn_s_barrier()
#define SB0 __builtin_amdgcn_sched_barrier(0)
#define LGKM0 asm volatile("s_waitcnt lgkmcnt(0)" ::: "memory")
#define VMW0 asm volatile("s_waitcnt vmcnt(0)" ::: "memory")

template <int BM, int EPI>
__global__ __launch_bounds__(512, 2) void k_gemm(const u16* __restrict__ A,
                                                 const u16* __restrict__ Bt,
                                                 float* __restrict__ Cout,
                                                 int Nn, int nxt,
                                                 const float* __restrict__ qb,
                                                 const float* __restrict__ kb,
                                                 const float* __restrict__ vb,
                                                 u16* __restrict__ Qo,
                                                 u16* __restrict__ Ko,
                                                 u16* __restrict__ Vo) {
  constexpr int NA64 = BM / 64;                 // full 64-row A units
  constexpr bool HAS_A2 = (BM % 64) != 0;       // 32-row tail
  constexpr int NFR = BM / 32;                  // m-frags per wave
  constexpr int MHA = (NFR + 1) / 2;            // first-half frags
  constexpr int MHB = NFR - MHA;                // second-half frags
  constexpr int ISS = NA64 + (HAS_A2 ? 2 : 0) + 4;  // vmem issues per tile
  constexpr int LROWS = BM + 256;
  __shared__ __align__(16) u16 L[2 * LROWS * 64];
  const int K = 3584, NKT = 56;
  const int tid = threadIdx.x;
  const int lane = tid & 63;
  const int w = tid >> 6;
  const int lr = lane & 15, lh = lane >> 4, lh8 = lh * 8;
  const int swz = (lr & 7) << 3;
  const int wr = w >> 2, wc = w & 3;  // 2 M-waves x 4 N-waves

  // bijective XCD swizzle (m204)
  const int nwg = gridDim.x;
  const int bid = blockIdx.x;
  const int q8 = nwg >> 3, r8 = nwg & 7;
  const int xcd = bid & 7, idx = bid >> 3;
  const int lb = (xcd < r8 ? xcd * (q8 + 1) : r8 * (q8 + 1) + (xcd - r8) * q8) + idx;
  const size_t m0 = (size_t)(lb / nxt) * BM;
  const size_t n0 = (size_t)(lb % nxt) << 8;

  const u16* __restrict__ Ab = A + m0 * K;
  const u16* __restrict__ Bb = Bt + n0 * K;

  const int srow = tid >> 3, scol8 = tid & 7;
  auto stg = [&](int buf, int u, int kt) {  // 64-row units: u<NA64 A, else B
    if (kt >= NKT) return;
    const u16* src;
    int ldsrow;
    if (u < NA64) {
      src = Ab + (size_t)(u * 64 + srow) * K;
      ldsrow = u * 64 + srow;
    } else {
      src = Bb + (size_t)((u - NA64) * 64 + srow) * K;
      ldsrow = BM + (u - NA64) * 64 + srow;
    }
    gload16(src + kt * 64 + scol8 * 8, &L[buf * (LROWS * 64) + ldsrow * 64 + scol8 * 8]);
  };
  auto stgA2 = [&](int buf, int kt) {  // 32-row tail, 2 width-4 issues (all waves)
    if constexpr (HAS_A2) {
      if (kt >= NKT) return;
      int c2 = (tid & 31) * 2;
#pragma unroll
      for (int jj = 0; jj < 2; ++jj) {
        int rr = NA64 * 64 + jj * 16 + (tid >> 5);
        gload4(Ab + (size_t)rr * K + kt * 64 + c2,
               &L[buf * (LROWS * 64) + rr * 64 + c2]);
      }
    }
  };
  auto vmw = [&]() {
    if constexpr (ISS == 8) { asm volatile("s_waitcnt vmcnt(6)" ::: "memory"); }
    else if constexpr (ISS == 7) { asm volatile("s_waitcnt vmcnt(5)" ::: "memory"); }
    else { asm volatile("s_waitcnt vmcnt(4)" ::: "memory"); }
  };

  f32x4 acc[NFR][4];
#pragma unroll
  for (int i = 0; i < NFR; i++)
#pragma unroll
    for (int j = 0; j < 4; j++) acc[i][j] = f32x4{0.f, 0.f, 0.f, 0.f};

  bf16x8 afA[MHA][2], afB[MHB][2], bq[2][2];

  auto rdA = [&](auto& arr, int LB, int mbase) {
    constexpr int CNT = sizeof(arr) / sizeof(arr[0]);
#pragma unroll
    for (int mm = 0; mm < CNT; ++mm)
#pragma unroll
      for (int kk = 0; kk < 2; ++kk)
        arr[mm][kk] = *(const bf16x8*)&L[LB + (wr * (BM / 2) + (mbase + mm) * 16 + lr) * 64 +
                                         ((kk * 32 + lh8) ^ swz)];
  };
  auto rdB = [&](int LB, int qbase) {
#pragma unroll
    for (int j = 0; j < 2; ++j)
#pragma unroll
      for (int kk = 0; kk < 2; ++kk)
        bq[j][kk] = *(const bf16x8*)&L[LB + (BM + (qbase + j) * 64 + wc * 16 + lr) * 64 +
                                       ((kk * 32 + lh8) ^ swz)];
  };
  auto mm4 = [&](auto& af, int mbase, int qbase) {
    constexpr int CNT = sizeof(af) / sizeof(af[0]);
    __builtin_amdgcn_s_setprio(1);
#pragma unroll
    for (int mm = 0; mm < CNT; ++mm)
#pragma unroll
      for (int j = 0; j < 2; ++j)
#pragma unroll
        for (int kk = 0; kk < 2; ++kk)
          acc[mbase + mm][qbase + j] = __builtin_amdgcn_mfma_f32_16x16x32_bf16(
              af[mm][kk], bq[j][kk], acc[mbase + mm][qbase + j], 0, 0, 0);
    __builtin_amdgcn_s_setprio(0);
  };

  // prologue: tile0 all units; tile1 all except B2,B3; counted wait drains tile0.
#pragma unroll
  for (int u = 0; u < NA64 + 4; ++u) stg(0, u, 0);
  stgA2(0, 0);
  stg(1, NA64 + 0, 1); stg(1, NA64 + 1, 1);
#pragma unroll
  for (int u = 0; u < NA64; ++u) stg(1, u, 1);
  stgA2(1, 1);
  vmw();
  BARR;

  for (int T = 0; T < NKT; ++T) {
    const int cur = T & 1;
    const int LB = cur * (LROWS * 64);
    // P0
    rdA(afA, LB, 0);
    rdB(LB, 0);
    stg(cur ^ 1, NA64 + 2, T + 1);
    stg(cur ^ 1, NA64 + 3, T + 1);
    BARR; LGKM0;
    mm4(afA, 0, 0);
    BARR;
    // P1
    rdA(afB, LB, MHA);
    stg(cur, NA64 + 0, T + 2);
    stg(cur, NA64 + 1, T + 2);
    BARR; LGKM0;
    mm4(afB, MHA, 0);
    BARR;
    // P2
    rdB(LB, 2);
    stg(cur, 0, T + 2);
    stg(cur, 1, T + 2);
    BARR; LGKM0;
    mm4(afA, 0, 2);
    BARR;
    // P3
    if constexpr (NA64 == 3) stg(cur, 2, T + 2);
    stgA2(cur, T + 2);
    if (T + 2 < NKT) { vmw(); } else { VMW0; }
    BARR;
    mm4(afB, MHA, 2);
    BARR;
  }

  if constexpr (EPI == 0) {
    const size_t Nsz = (size_t)Nn;
#pragma unroll
    for (int m = 0; m < NFR; ++m) {
      size_t row = m0 + wr * (BM / 2) + m * 16 + lh * 4;
      if (row < 2048) {
#pragma unroll
        for (int p = 0; p < 4; ++p) {
          size_t col = n0 + p * 64 + wc * 16 + lr;
#pragma unroll
          for (int r = 0; r < 4; ++r) Cout[(row + r) * Nsz + col] = acc[m][p][r];
        }
      }
    }
  } else {
    const int ntile = (int)(n0 >> 8);  // 0..17
#pragma unroll
    for (int m = 0; m < NFR; ++m) {
      size_t row = m0 + wr * (BM / 2) + m * 16 + lh * 4;
      if (row >= 2048) continue;
#pragma unroll
      for (int p = 0; p < 4; ++p) {
        int col = (int)n0 + p * 64 + wc * 16 + lr;
        if (ntile < 14) {  // Q (unroped — attn ropes in-register)
          int hh = col >> 7, d = col & 127;
          float bias = qb[col];
#pragma unroll
          for (int r = 0; r < 4; ++r)
            Qo[((size_t)hh * S_N + row + r) * D_N + d] = f2bf(acc[m][p][r] + bias);
        } else if (ntile < 16) {  // K (unroped, unswizzled — k_ropek finishes)
          int cc = col - E_N, kvh = cc >> 7, d = cc & 127;
          float bias = kb[cc];
#pragma unroll
          for (int r = 0; r < 4; ++r)
            Ko[((size_t)kvh * S_N + row + r) * D_N + d] = f2bf(acc[m][p][r] + bias);
        } else {  // V -> transposed [cc][s], within-64 swizzle; 4-run contiguous in s
          int cc = col - 4096;
          float bias = vb[cc];
          int s = (int)row;
          int pos = (s & ~63) | ((s & 63) ^ ((cc & 7) << 3));
          u16x4 vv;
#pragma unroll
          for (int r = 0; r < 4; ++r) vv[r] = f2bf(acc[m][p][r] + bias);
          *(u16x4*)(Vo + (size_t)cc * S_N + pos) = vv;
        }
      }
    }
  }
}

// ---------------- RoPE in-place on bf16 K only; writes swizzled ----------------
__global__ __launch_bounds__(256) void k_ropek(u16* __restrict__ Kb,
                                               const float* __restrict__ cosb,
                                               const float* __restrict__ sinb) {
  int s = blockIdx.x;
  int kvh = threadIdx.x >> 6, lane = threadIdx.x & 63;
  float c0 = cosb[s * D_N + lane], c1 = cosb[s * D_N + lane + 64];
  float s0 = sinb[s * D_N + lane], s1 = sinb[s * D_N + lane + 64];
  u16* p = Kb + ((size_t)kvh * S_N + s) * D_N;
  float x0 = bf2f(p[lane]), x1 = bf2f(p[lane + 64]);
  float y0 = x0 * c0 - x1 * s0;
  float y1 = x1 * c1 + x0 * s1;
  int sw = (s & 15) << 3;
  p[lane ^ sw] = f2bf(y0);
  p[(lane + 64) ^ sw] = f2bf(y1);
}

// ---------------- flash attention, GQA, causal; Q-RoPE fused in prologue ----------------
__global__ __launch_bounds__(256, 2) void k_attn(const u16* __restrict__ Q,
                                                 const u16* __restrict__ Kc,
                                                 const u16* __restrict__ Vt,
                                                 const float* __restrict__ cosb,
                                                 const float* __restrict__ sinb,
                                                 u16* __restrict__ Aout) {
  __shared__ __align__(16) u16 Klds[2][64 * 128];
  __shared__ __align__(16) u16 Vlds[2][128 * 64];
  const int h = blockIdx.y;
  const int kvh = h / 7;  // H/KVH = 7
  const int qt = (15 - blockIdx.x + ((blockIdx.y & 16) ? 8 : 0)) & 15;
  const int q0 = qt * 128;
  const int tid = threadIdx.x, w = tid >> 6, lane = tid & 63;
  const int l31 = lane & 31, hi = lane >> 5;
  const int hi8 = hi * 8;
  const int swK = (l31 & 15) << 3;  // K-read swizzle
  const int swV = (l31 & 7) << 3;   // V-read swizzle
  const int qloc = w * 32 + l31;
  const int qrow = q0 + qloc;

  // Q fragments with in-register RoPE: frag f (d<64) pairs with f+4 (d+64).
  bf16x8 qf[8];
  {
    const u16* qp = Q + ((size_t)h * S_N + qrow) * D_N + hi8;
    const float* cb = cosb + (size_t)qrow * D_N + hi8;
    const float* sb = sinb + (size_t)qrow * D_N + hi8;
#pragma unroll
    for (int f = 0; f < 4; ++f) {
      u16x8 ulo = __builtin_bit_cast(u16x8, *(const bf16x8*)(qp + f * 16));
      u16x8 uhi = __builtin_bit_cast(u16x8, *(const bf16x8*)(qp + (f + 4) * 16));
      u16x8 olo, ohi;
#pragma unroll
      for (int e = 0; e < 8; ++e) {
        float xl = bf2f(ulo[e]), xh = bf2f(uhi[e]);
        float cl = cb[f * 16 + e], sl = sb[f * 16 + e];
        float ch = cb[(f + 4) * 16 + e], sh = sb[(f + 4) * 16 + e];
        olo[e] = f2bf(xl * cl - xh * sl);
        ohi[e] = f2bf(xh * ch + xl * sh);
      }
      qf[f] = __builtin_bit_cast(bf16x8, olo);
      qf[f + 4] = __builtin_bit_cast(bf16x8, ohi);
    }
  }

  f32x16 o[4];
#pragma unroll
  for (int i = 0; i < 4; i++)
#pragma unroll
    for (int r = 0; r < 16; r++) o[i][r] = 0.f;

  float m2 = -3.0e38f;
  float lsum = 0.f;
  const float msc = 0.12751743f;  // 1/sqrt(128) * log2(e)

  auto stageKV = [&](int buf, int t) {
    const u16* ks = Kc + ((size_t)kvh * S_N + t * 64) * D_N;
#pragma unroll
    for (int j = 0; j < 4; ++j)
      gload16(ks + (j * 256 + tid) * 8, &Klds[buf][(j * 256 + tid) * 8]);
    const u16* vs = Vt + (size_t)kvh * D_N * S_N + t * 64;
#pragma unroll
    for (int j = 0; j < 4; ++j) {
      int idx = j * 256 + tid;
      int dd = idx >> 3, cw = idx & 7;
      gload16(vs + (size_t)dd * S_N + cw * 8, &Vlds[buf][idx * 8]);
    }
  };

  const int nt = 2 * qt + 2;
  stageKV(0, 0);
  for (int t = 0; t < nt; ++t) {
    const int cur = t & 1;
    if (t + 1 < nt) {
      stageKV(cur ^ 1, t + 1);
      asm volatile("s_waitcnt vmcnt(8)" ::: "memory");  // tile t resident (FIFO)
    } else {
      asm volatile("s_waitcnt vmcnt(0)" ::: "memory");
    }
    SB0; BARR; SB0;
    f32x16 sacc[2];
#pragma unroll
    for (int i = 0; i < 2; i++)
#pragma unroll
      for (int r = 0; r < 16; r++) sacc[i][r] = 0.f;
    __builtin_amdgcn_s_setprio(1);
#pragma unroll
    for (int dstep = 0; dstep < 8; ++dstep)
#pragma unroll
      for (int ksub = 0; ksub < 2; ++ksub) {
        bf16x8 ka =
            *(const bf16x8*)&Klds[cur][(ksub * 32 + l31) * D_N + ((dstep * 16 + hi8) ^ swK)];
        sacc[ksub] = __builtin_amdgcn_mfma_f32_32x32x16_bf16(ka, qf[dstep], sacc[ksub], 0, 0, 0);
      }
    __builtin_amdgcn_s_setprio(0);
    if (t >= nt - 2) {
#pragma unroll
      for (int ksub = 0; ksub < 2; ++ksub)
#pragma unroll
        for (int r = 0; r < 16; ++r) {
          int kvg = t * 64 + ksub * 32 + (r & 3) + 8 * (r >> 2) + 4 * hi;
          sacc[ksub][r] = (kvg <= qrow) ? sacc[ksub][r] * msc : -3.0e38f;
        }
    } else {
#pragma unroll
      for (int ksub = 0; ksub < 2; ++ksub)
#pragma unroll
        for (int r = 0; r < 16; ++r) sacc[ksub][r] *= msc;
    }
    float tmax = fmaxf(vmax16(sacc[0]), vmax16(sacc[1]));
    tmax = fmaxf(tmax, __shfl_xor(tmax, 32));
    if (__any(tmax > m2 + 8.0f)) {
      float m2new = fmaxf(m2, tmax);
      float scl = __builtin_amdgcn_exp2f(m2 - m2new);
#pragma unroll
      for (int i = 0; i < 4; i++)
#pragma unroll
        for (int r = 0; r < 16; r++) o[i][r] *= scl;
      lsum *= scl;
      m2 = m2new;
    }
#pragma unroll
    for (int ksub = 0; ksub < 2; ++ksub) {
#pragma unroll
      for (int r = 0; r < 16; ++r)
        sacc[ksub][r] = __builtin_amdgcn_exp2f(sacc[ksub][r] - m2);
      lsum += vsum16(sacc[ksub]);
    }
    __builtin_amdgcn_s_setprio(1);
#pragma unroll
    for (int ksub = 0; ksub < 2; ++ksub) {
      u32 pw[8];
#pragma unroll
      for (int i = 0; i < 8; ++i) pw[i] = cvt_pk_bf16(sacc[ksub][2 * i], sacc[ksub][2 * i + 1]);
      pl32swap(pw[0], pw[2]);
      pl32swap(pw[1], pw[3]);
      pl32swap(pw[4], pw[6]);
      pl32swap(pw[5], pw[7]);
#pragma unroll
      for (int j = 0; j < 2; ++j) {
        u32x4 fw = {pw[j * 4 + 0], pw[j * 4 + 1], pw[j * 4 + 2], pw[j * 4 + 3]};
        bf16x8 pb = __builtin_bit_cast(bf16x8, fw);
#pragma unroll
        for (int dsub = 0; dsub < 4; ++dsub) {
          bf16x8 va = *(const bf16x8*)&Vlds[cur][(dsub * 32 + l31) * 64 +
                                                 ((ksub * 32 + j * 16 + hi8) ^ swV)];
          o[dsub] = __builtin_amdgcn_mfma_f32_32x32x16_bf16(va, pb, o[dsub], 0, 0, 0);
        }
      }
    }
    __builtin_amdgcn_s_setprio(0);
    SB0; BARR; SB0;
  }
  float lt = lsum + __shfl_xor(lsum, 32);
  float ri = 1.0f / lt;
  u16* op = Aout + (size_t)qrow * E_N + h * D_N;
  const int sw2 = (qrow & 7) << 3;  // GEMM-A pre-swizzle
#pragma unroll
  for (int dsub = 0; dsub < 4; ++dsub)
#pragma unroll
    for (int g = 0; g < 4; ++g) {
      int dbase = dsub * 32 + 8 * g + 4 * hi;
      u32x2 wv;
      wv[0] = (u32)f2bf(o[dsub][g * 4 + 0] * ri) | ((u32)f2bf(o[dsub][g * 4 + 1] * ri) << 16);
      wv[1] = (u32)f2bf(o[dsub][g * 4 + 2] * ri) | ((u32)f2bf(o[dsub][g * 4 + 3] * ri) << 16);
      *(u32x2*)(op + (dbase ^ sw2)) = wv;
    }
}

extern "C" void kernel_launch(void* const* d_in, const int* in_sizes, int n_in,
                              void* d_out, int out_size, void* d_ws, size_t ws_size,
                              hipStream_t stream) {
  const float* hs   = (const float*)d_in[0];
  const float* cosb = (const float*)d_in[1];
  const float* sinb = (const float*)d_in[2];
  // d_in[3] = attn_mask (causal tril — applied analytically)
  const float* qw = (const float*)d_in[4];
  const float* qb = (const float*)d_in[5];
  const float* kw = (const float*)d_in[6];
  const float* kb = (const float*)d_in[7];
  const float* vw = (const float*)d_in[8];
  const float* vb = (const float*)d_in[9];
  const float* ow = (const float*)d_in[10];
  float* outp = (float*)d_out;

  char* ws = (char*)d_ws;
  u16* hsb    = (u16*)(ws);                       // 2048x3584 bf16 (swz)           14.7MB
  u16* wt     = (u16*)(ws + 14680064);            // 4608x3584 bf16 (swz)             33MB
  u16* wt2    = (u16*)(ws + 47710208);            // 3584x3584 ow^T bf16 (swz)      25.7MB
  u16* attn_o = (u16*)(ws + 73400320);            // 2048x3584 bf16 (swz)           14.7MB
  u16* Qb     = (u16*)(ws + 88080384);            // [28][2048][128] (unroped)      14.7MB
  u16* Kb     = (u16*)(ws + 102760448);           // [4][2048][128] (swz after rope)  2MB
  u16* Vtb    = (u16*)(ws + 104857600);           // [512][2048] (swz within-64)      2MB

  // 1. hs -> bf16 (GEMM-swizzled)
  k_hs_bf16_swz<<<dim3(917504 / 256), dim3(256), 0, stream>>>(hs, hsb);
  // 2. merged qw/kw/vw/ow transposes (GEMM-swizzled)
  k_wtrans<<<dim3(128, 56), dim3(256), 0, stream>>>(qw, kw, vw, ow, wt, wt2);
  // 3. QKV GEMM, BM=160: 13x18 = 234 blocks (91% CU fill), fused bias+layout epilogue
  k_gemm<160, 1><<<dim3(234), dim3(512), 0, stream>>>(hsb, wt, nullptr, 4608, 18,
                                                      qb, kb, vb, Qb, Kb, Vtb);
  // 4. RoPE in-place on K (swizzled); Q roped in-register inside k_attn
  k_ropek<<<dim3(2048), dim3(256), 0, stream>>>(Kb, cosb, sinb);
  // 5. attention -> attn_o (bf16, GEMM-swizzled)
  k_attn<<<dim3(16, 28), dim3(256), 0, stream>>>(Qb, Kb, Vtb, cosb, sinb, attn_o);
  // 6. output projection, BM=128: 224 blocks
  k_gemm<128, 0><<<dim3(224), dim3(512), 0, stream>>>(attn_o, wt2, outp, 3584, 14,
                                                      nullptr, nullptr, nullptr,
                                                      nullptr, nullptr, nullptr);
}

// Round 14
// 242.873 us; speedup vs baseline: 1.1330x; 1.0238x over previous
//
#include <hip/hip_runtime.h>

#define H_N 28
#define KVH_N 4
#define D_N 128
#define S_N 2048
#define E_N 3584
#define NQKV 4608

typedef unsigned short u16;
typedef unsigned int u32;
typedef __bf16 bf16x8 __attribute__((ext_vector_type(8)));
typedef float f32x4 __attribute__((ext_vector_type(4)));
typedef float f32x16 __attribute__((ext_vector_type(16)));
typedef unsigned short u16x4 __attribute__((ext_vector_type(4)));
typedef unsigned short u16x8 __attribute__((ext_vector_type(8)));
typedef unsigned int u32x2 __attribute__((ext_vector_type(2)));
typedef unsigned int u32x4 __attribute__((ext_vector_type(4)));

typedef __attribute__((address_space(1))) void gvoid_t;
typedef __attribute__((address_space(3))) void lvoid_t;

static __device__ __forceinline__ u16 f2bf(float f) {
  __bf16 h = (__bf16)f;
  return __builtin_bit_cast(unsigned short, h);
}

static __device__ __forceinline__ float bf2f(u16 b) {
  u32 u = (u32)b << 16;
  return __builtin_bit_cast(float, u);
}

static __device__ __forceinline__ void gload16(const void* g, void* l) {
  __builtin_amdgcn_global_load_lds((gvoid_t*)g, (lvoid_t*)l, 16, 0, 0);
}

static __device__ __forceinline__ void gload4(const void* g, void* l) {
  __builtin_amdgcn_global_load_lds((gvoid_t*)g, (lvoid_t*)l, 4, 0, 0);
}

static __device__ __forceinline__ u32 cvt_pk_bf16(float lo, float hi) {
  u32 r;
  asm("v_cvt_pk_bf16_f32 %0, %1, %2" : "=v"(r) : "v"(lo), "v"(hi));
  return r;
}

static __device__ __forceinline__ void pl32swap(u32& a, u32& b) {
  asm volatile("v_permlane32_swap_b32 %0, %1" : "+v"(a), "+v"(b));
}

static __device__ __forceinline__ float vmax16(f32x16 v) {
  float a = fmaxf(fmaxf(v[0], v[1]), fmaxf(v[2], v[3]));
  float b = fmaxf(fmaxf(v[4], v[5]), fmaxf(v[6], v[7]));
  float c = fmaxf(fmaxf(v[8], v[9]), fmaxf(v[10], v[11]));
  float d = fmaxf(fmaxf(v[12], v[13]), fmaxf(v[14], v[15]));
  return fmaxf(fmaxf(a, b), fmaxf(c, d));
}

static __device__ __forceinline__ float vsum16(f32x16 v) {
  float a = (v[0] + v[1]) + (v[2] + v[3]);
  float b = (v[4] + v[5]) + (v[6] + v[7]);
  float c = (v[8] + v[9]) + (v[10] + v[11]);
  float d = (v[12] + v[13]) + (v[14] + v[15]);
  return (a + b) + (c + d);
}

// ---------------- hs f32 -> bf16, GEMM-swizzled (8-elem group ^= row&7) ----------------
__global__ __launch_bounds__(256) void k_hs_bf16_swz(const float* __restrict__ in,
                                                     u16* __restrict__ out) {
  int g = blockIdx.x * 256 + threadIdx.x;  // 2048*3584/8 groups
  int row = g / 448, c8 = g % 448;
  const float4* p = (const float4*)(in + (size_t)g * 8);
  float4 a = p[0], b = p[1];
  u16x8 r;
  r[0] = f2bf(a.x); r[1] = f2bf(a.y); r[2] = f2bf(a.z); r[3] = f2bf(a.w);
  r[4] = f2bf(b.x); r[5] = f2bf(b.y); r[6] = f2bf(b.z); r[7] = f2bf(b.w);
  int dc8 = c8 ^ (row & 7);
  *(u16x8*)(out + (size_t)row * E_N + dc8 * 8) = r;
}

// -------- merged qw/kw/vw/ow transpose: one launch, bx selects source segment ----------
__global__ __launch_bounds__(256) void k_wtrans(const float* __restrict__ qw,
                                                const float* __restrict__ kw,
                                                const float* __restrict__ vw,
                                                const float* __restrict__ ow,
                                                u16* __restrict__ wt,
                                                u16* __restrict__ wt2) {
  __shared__ float t[64][65];
  int bx = blockIdx.x;
  const float* in;
  u16* out;
  int C, c0;
  if (bx < 56) {
    in = qw; out = wt; C = 3584; c0 = bx * 64;
  } else if (bx < 64) {
    in = kw; out = wt + (size_t)3584 * 3584; C = 512; c0 = (bx - 56) * 64;
  } else if (bx < 72) {
    in = vw; out = wt + (size_t)4096 * 3584; C = 512; c0 = (bx - 64) * 64;
  } else {
    in = ow; out = wt2; C = 3584; c0 = (bx - 72) * 64;
  }
  int r0 = blockIdx.y * 64;
  int lr = threadIdx.x >> 6, lc = threadIdx.x & 63;
#pragma unroll
  for (int i = 0; i < 64; i += 4)
    t[lr + i][lc] = in[(size_t)(r0 + lr + i) * C + c0 + lc];
  __syncthreads();
#pragma unroll
  for (int i = 0; i < 64; i += 4) {
    int orow = c0 + lr + i;
    int sw = (orow & 7) << 3;
    out[(size_t)orow * 3584 + r0 + (lc ^ sw)] = f2bf(t[lc][lr + i]);
  }
}

// =================== GEMM BMx256, BK=64, 8 waves, balanced 4-phase =====================
// BM in {128, 160, 192}. A tail (BM=160): 32-row unit staged via 2x width-4
// global_load_lds (uniform per-wave issue count). Issues/tile: 6/8/7 -> counted
// vmcnt(ISS-2) at P3 keeps exactly tile T+1 resident (FIFO-traced).
// Phases (m-frags split MHA+MHB): P0 rdA-halfA+B q01; P1 rdA-halfB; P2 rdB q23; P3 none.
// Stage: P0:(T+1).B2,B3->buf^1  P1:(T+2).B0,B1  P2:(T+2).A0,A1  P3:(T+2).A2/tail
// EPI=1: fused QKV epilogue (Q/K unroped bf16; V transposed+swizzled).
#define BARR __builtin_amdgcn_s_barrier()
#define SB0 __builtin_amdgcn_sched_barrier(0)
#define LGKM0 asm volatile("s_waitcnt lgkmcnt(0)" ::: "memory")
#define VMW0 asm volatile("s_waitcnt vmcnt(0)" ::: "memory")

template <int BM, int EPI>
__global__ __launch_bounds__(512, 2) void k_gemm(const u16* __restrict__ A,
                                                 const u16* __restrict__ Bt,
                                                 float* __restrict__ Cout,
                                                 int Nn, int nxt,
                                                 const float* __restrict__ qb,
                                                 const float* __restrict__ kb,
                                                 const float* __restrict__ vb,
                                                 u16* __restrict__ Qo,
                                                 u16* __restrict__ Ko,
                                                 u16* __restrict__ Vo) {
  constexpr int NA64 = BM / 64;                 // full 64-row A units
  constexpr bool HAS_A2 = (BM % 64) != 0;       // 32-row tail
  constexpr int NFR = BM / 32;                  // m-frags per wave
  constexpr int MHA = (NFR + 1) / 2;            // first-half frags
  constexpr int MHB = NFR - MHA;                // second-half frags
  constexpr int ISS = NA64 + (HAS_A2 ? 2 : 0) + 4;  // vmem issues per tile
  constexpr int LROWS = BM + 256;
  __shared__ __align__(16) u16 L[2 * LROWS * 64];
  const int K = 3584, NKT = 56;
  const int tid = threadIdx.x;
  const int lane = tid & 63;
  const int w = tid >> 6;
  const int lr = lane & 15, lh = lane >> 4, lh8 = lh * 8;
  const int swz = (lr & 7) << 3;
  const int wr = w >> 2, wc = w & 3;  // 2 M-waves x 4 N-waves

  // bijective XCD swizzle (m204)
  const int nwg = gridDim.x;
  const int bid = blockIdx.x;
  const int q8 = nwg >> 3, r8 = nwg & 7;
  const int xcd = bid & 7, idx = bid >> 3;
  const int lb = (xcd < r8 ? xcd * (q8 + 1) : r8 * (q8 + 1) + (xcd - r8) * q8) + idx;
  const size_t m0 = (size_t)(lb / nxt) * BM;
  const size_t n0 = (size_t)(lb % nxt) << 8;

  const u16* __restrict__ Ab = A + m0 * K;
  const u16* __restrict__ Bb = Bt + n0 * K;

  const int srow = tid >> 3, scol8 = tid & 7;
  auto stg = [&](int buf, int u, int kt) {  // 64-row units: u<NA64 A, else B
    if (kt >= NKT) return;
    const u16* src;
    int ldsrow;
    if (u < NA64) {
      src = Ab + (size_t)(u * 64 + srow) * K;
      ldsrow = u * 64 + srow;
    } else {
      src = Bb + (size_t)((u - NA64) * 64 + srow) * K;
      ldsrow = BM + (u - NA64) * 64 + srow;
    }
    gload16(src + kt * 64 + scol8 * 8, &L[buf * (LROWS * 64) + ldsrow * 64 + scol8 * 8]);
  };
  auto stgA2 = [&](int buf, int kt) {  // 32-row tail, 2 width-4 issues (all waves)
    if constexpr (HAS_A2) {
      if (kt >= NKT) return;
      int c2 = (tid & 31) * 2;
#pragma unroll
      for (int jj = 0; jj < 2; ++jj) {
        int rr = NA64 * 64 + jj * 16 + (tid >> 5);
        gload4(Ab + (size_t)rr * K + kt * 64 + c2,
               &L[buf * (LROWS * 64) + rr * 64 + c2]);
      }
    }
  };
  auto vmw = [&]() {
    if constexpr (ISS == 8) { asm volatile("s_waitcnt vmcnt(6)" ::: "memory"); }
    else if constexpr (ISS == 7) { asm volatile("s_waitcnt vmcnt(5)" ::: "memory"); }
    else { asm volatile("s_waitcnt vmcnt(4)" ::: "memory"); }
  };

  f32x4 acc[NFR][4];
#pragma unroll
  for (int i = 0; i < NFR; i++)
#pragma unroll
    for (int j = 0; j < 4; j++) acc[i][j] = f32x4{0.f, 0.f, 0.f, 0.f};

  bf16x8 afA[MHA][2], afB[MHB][2], bq[2][2];

  auto rdA = [&](auto& arr, int LB, int mbase) {
    constexpr int CNT = sizeof(arr) / sizeof(arr[0]);
#pragma unroll
    for (int mm = 0; mm < CNT; ++mm)
#pragma unroll
      for (int kk = 0; kk < 2; ++kk)
        arr[mm][kk] = *(const bf16x8*)&L[LB + (wr * (BM / 2) + (mbase + mm) * 16 + lr) * 64 +
                                         ((kk * 32 + lh8) ^ swz)];
  };
  auto rdB = [&](int LB, int qbase) {
#pragma unroll
    for (int j = 0; j < 2; ++j)
#pragma unroll
      for (int kk = 0; kk < 2; ++kk)
        bq[j][kk] = *(const bf16x8*)&L[LB + (BM + (qbase + j) * 64 + wc * 16 + lr) * 64 +
                                       ((kk * 32 + lh8) ^ swz)];
  };
  auto mm4 = [&](auto& af, int mbase, int qbase) {
    constexpr int CNT = sizeof(af) / sizeof(af[0]);
    __builtin_amdgcn_s_setprio(1);
#pragma unroll
    for (int mm = 0; mm < CNT; ++mm)
#pragma unroll
      for (int j = 0; j < 2; ++j)
#pragma unroll
        for (int kk = 0; kk < 2; ++kk)
          acc[mbase + mm][qbase + j] = __builtin_amdgcn_mfma_f32_16x16x32_bf16(
              af[mm][kk], bq[j][kk], acc[mbase + mm][qbase + j], 0, 0, 0);
    __builtin_amdgcn_s_setprio(0);
  };

  // prologue: tile0 all units; tile1 all except B2,B3; counted wait drains tile0.
#pragma unroll
  for (int u = 0; u < NA64 + 4; ++u) stg(0, u, 0);
  stgA2(0, 0);
  stg(1, NA64 + 0, 1); stg(1, NA64 + 1, 1);
#pragma unroll
  for (int u = 0; u < NA64; ++u) stg(1, u, 1);
  stgA2(1, 1);
  vmw();
  BARR;

  for (int T = 0; T < NKT; ++T) {
    const int cur = T & 1;
    const int LB = cur * (LROWS * 64);
    // P0
    rdA(afA, LB, 0);
    rdB(LB, 0);
    stg(cur ^ 1, NA64 + 2, T + 1);
    stg(cur ^ 1, NA64 + 3, T + 1);
    BARR; LGKM0;
    mm4(afA, 0, 0);
    BARR;
    // P1
    rdA(afB, LB, MHA);
    stg(cur, NA64 + 0, T + 2);
    stg(cur, NA64 + 1, T + 2);
    BARR; LGKM0;
    mm4(afB, MHA, 0);
    BARR;
    // P2
    rdB(LB, 2);
    stg(cur, 0, T + 2);
    stg(cur, 1, T + 2);
    BARR; LGKM0;
    mm4(afA, 0, 2);
    BARR;
    // P3
    if constexpr (NA64 == 3) stg(cur, 2, T + 2);
    stgA2(cur, T + 2);
    if (T + 2 < NKT) { vmw(); } else { VMW0; }
    BARR;
    mm4(afB, MHA, 2);
    BARR;
  }

  if constexpr (EPI == 0) {
    const size_t Nsz = (size_t)Nn;
#pragma unroll
    for (int m = 0; m < NFR; ++m) {
      size_t row = m0 + wr * (BM / 2) + m * 16 + lh * 4;
      if (row < 2048) {
#pragma unroll
        for (int p = 0; p < 4; ++p) {
          size_t col = n0 + p * 64 + wc * 16 + lr;
#pragma unroll
          for (int r = 0; r < 4; ++r) Cout[(row + r) * Nsz + col] = acc[m][p][r];
        }
      }
    }
  } else {
    const int ntile = (int)(n0 >> 8);  // 0..17
#pragma unroll
    for (int m = 0; m < NFR; ++m) {
      size_t row = m0 + wr * (BM / 2) + m * 16 + lh * 4;
      if (row >= 2048) continue;
#pragma unroll
      for (int p = 0; p < 4; ++p) {
        int col = (int)n0 + p * 64 + wc * 16 + lr;
        if (ntile < 14) {  // Q (unroped — attn ropes in-register)
          int hh = col >> 7, d = col & 127;
          float bias = qb[col];
#pragma unroll
          for (int r = 0; r < 4; ++r)
            Qo[((size_t)hh * S_N + row + r) * D_N + d] = f2bf(acc[m][p][r] + bias);
        } else if (ntile < 16) {  // K (unroped, unswizzled — k_ropek finishes)
          int cc = col - E_N, kvh = cc >> 7, d = cc & 127;
          float bias = kb[cc];
#pragma unroll
          for (int r = 0; r < 4; ++r)
            Ko[((size_t)kvh * S_N + row + r) * D_N + d] = f2bf(acc[m][p][r] + bias);
        } else {  // V -> transposed [cc][s], within-64 swizzle; 4-run contiguous in s
          int cc = col - 4096;
          float bias = vb[cc];
          int s = (int)row;
          int pos = (s & ~63) | ((s & 63) ^ ((cc & 7) << 3));
          u16x4 vv;
#pragma unroll
          for (int r = 0; r < 4; ++r) vv[r] = f2bf(acc[m][p][r] + bias);
          *(u16x4*)(Vo + (size_t)cc * S_N + pos) = vv;
        }
      }
    }
  }
}

// ---------------- RoPE in-place on bf16 K only; writes swizzled ----------------
__global__ __launch_bounds__(256) void k_ropek(u16* __restrict__ Kb,
                                               const float* __restrict__ cosb,
                                               const float* __restrict__ sinb) {
  int s = blockIdx.x;
  int kvh = threadIdx.x >> 6, lane = threadIdx.x & 63;
  float c0 = cosb[s * D_N + lane], c1 = cosb[s * D_N + lane + 64];
  float s0 = sinb[s * D_N + lane], s1 = sinb[s * D_N + lane + 64];
  u16* p = Kb + ((size_t)kvh * S_N + s) * D_N;
  float x0 = bf2f(p[lane]), x1 = bf2f(p[lane + 64]);
  float y0 = x0 * c0 - x1 * s0;
  float y1 = x1 * c1 + x0 * s1;
  int sw = (s & 15) << 3;
  p[lane ^ sw] = f2bf(y0);
  p[(lane + 64) ^ sw] = f2bf(y1);
}

// ---------------- flash attention, GQA, causal; Q-RoPE fused in prologue ----------------
// qt map: constant-sum pairing — under round-robin bid->CU, CU k hosts bids k and
// k+256; qt(h<16)=15-bx, qt(h>=16)=bx => per-CU step sum == 15 (balanced makespan).
__global__ __launch_bounds__(256, 2) void k_attn(const u16* __restrict__ Q,
                                                 const u16* __restrict__ Kc,
                                                 const u16* __restrict__ Vt,
                                                 const float* __restrict__ cosb,
                                                 const float* __restrict__ sinb,
                                                 u16* __restrict__ Aout) {
  __shared__ __align__(16) u16 Klds[2][64 * 128];
  __shared__ __align__(16) u16 Vlds[2][128 * 64];
  const int h = blockIdx.y;
  const int kvh = h / 7;  // H/KVH = 7
  const int qt = (blockIdx.y & 16) ? (blockIdx.x & 15) : ((15 - blockIdx.x) & 15);
  const int q0 = qt * 128;
  const int tid = threadIdx.x, w = tid >> 6, lane = tid & 63;
  const int l31 = lane & 31, hi = lane >> 5;
  const int hi8 = hi * 8;
  const int swK = (l31 & 15) << 3;  // K-read swizzle
  const int swV = (l31 & 7) << 3;   // V-read swizzle
  const int qloc = w * 32 + l31;
  const int qrow = q0 + qloc;

  // Q fragments with in-register RoPE: frag f (d<64) pairs with f+4 (d+64).
  bf16x8 qf[8];
  {
    const u16* qp = Q + ((size_t)h * S_N + qrow) * D_N + hi8;
    const float* cb = cosb + (size_t)qrow * D_N + hi8;
    const float* sb = sinb + (size_t)qrow * D_N + hi8;
#pragma unroll
    for (int f = 0; f < 4; ++f) {
      u16x8 ulo = __builtin_bit_cast(u16x8, *(const bf16x8*)(qp + f * 16));
      u16x8 uhi = __builtin_bit_cast(u16x8, *(const bf16x8*)(qp + (f + 4) * 16));
      u16x8 olo, ohi;
#pragma unroll
      for (int e = 0; e < 8; ++e) {
        float xl = bf2f(ulo[e]), xh = bf2f(uhi[e]);
        float cl = cb[f * 16 + e], sl = sb[f * 16 + e];
        float ch = cb[(f + 4) * 16 + e], sh = sb[(f + 4) * 16 + e];
        olo[e] = f2bf(xl * cl - xh * sl);
        ohi[e] = f2bf(xh * ch + xl * sh);
      }
      qf[f] = __builtin_bit_cast(bf16x8, olo);
      qf[f + 4] = __builtin_bit_cast(bf16x8, ohi);
    }
  }

  f32x16 o[4];
#pragma unroll
  for (int i = 0; i < 4; i++)
#pragma unroll
    for (int r = 0; r < 16; r++) o[i][r] = 0.f;

  float m2 = -3.0e38f;
  float lsum = 0.f;
  const float msc = 0.12751743f;  // 1/sqrt(128) * log2(e)

  auto stageKV = [&](int buf, int t) {
    const u16* ks = Kc + ((size_t)kvh * S_N + t * 64) * D_N;
#pragma unroll
    for (int j = 0; j < 4; ++j)
      gload16(ks + (j * 256 + tid) * 8, &Klds[buf][(j * 256 + tid) * 8]);
    const u16* vs = Vt + (size_t)kvh * D_N * S_N + t * 64;
#pragma unroll
    for (int j = 0; j < 4; ++j) {
      int idx = j * 256 + tid;
      int dd = idx >> 3, cw = idx & 7;
      gload16(vs + (size_t)dd * S_N + cw * 8, &Vlds[buf][idx * 8]);
    }
  };

  const int nt = 2 * qt + 2;
  stageKV(0, 0);
  for (int t = 0; t < nt; ++t) {
    const int cur = t & 1;
    if (t + 1 < nt) {
      stageKV(cur ^ 1, t + 1);
      asm volatile("s_waitcnt vmcnt(8)" ::: "memory");  // tile t resident (FIFO)
    } else {
      asm volatile("s_waitcnt vmcnt(0)" ::: "memory");
    }
    SB0; BARR; SB0;
    f32x16 sacc[2];
#pragma unroll
    for (int i = 0; i < 2; i++)
#pragma unroll
      for (int r = 0; r < 16; r++) sacc[i][r] = 0.f;
    __builtin_amdgcn_s_setprio(1);
#pragma unroll
    for (int dstep = 0; dstep < 8; ++dstep)
#pragma unroll
      for (int ksub = 0; ksub < 2; ++ksub) {
        bf16x8 ka =
            *(const bf16x8*)&Klds[cur][(ksub * 32 + l31) * D_N + ((dstep * 16 + hi8) ^ swK)];
        sacc[ksub] = __builtin_amdgcn_mfma_f32_32x32x16_bf16(ka, qf[dstep], sacc[ksub], 0, 0, 0);
      }
    __builtin_amdgcn_s_setprio(0);
    if (t >= nt - 2) {
#pragma unroll
      for (int ksub = 0; ksub < 2; ++ksub)
#pragma unroll
        for (int r = 0; r < 16; ++r) {
          int kvg = t * 64 + ksub * 32 + (r & 3) + 8 * (r >> 2) + 4 * hi;
          sacc[ksub][r] = (kvg <= qrow) ? sacc[ksub][r] * msc : -3.0e38f;
        }
    } else {
#pragma unroll
      for (int ksub = 0; ksub < 2; ++ksub)
#pragma unroll
        for (int r = 0; r < 16; ++r) sacc[ksub][r] *= msc;
    }
    float tmax = fmaxf(vmax16(sacc[0]), vmax16(sacc[1]));
    tmax = fmaxf(tmax, __shfl_xor(tmax, 32));  // cross-half max (known-good)
    if (__any(tmax > m2 + 8.0f)) {
      float m2new = fmaxf(m2, tmax);
      float scl = __builtin_amdgcn_exp2f(m2 - m2new);
#pragma unroll
      for (int i = 0; i < 4; i++)
#pragma unroll
        for (int r = 0; r < 16; r++) o[i][r] *= scl;
      lsum *= scl;
      m2 = m2new;
    }
#pragma unroll
    for (int ksub = 0; ksub < 2; ++ksub) {
#pragma unroll
      for (int r = 0; r < 16; ++r)
        sacc[ksub][r] = __builtin_amdgcn_exp2f(sacc[ksub][r] - m2);
      lsum += vsum16(sacc[ksub]);
    }
    __builtin_amdgcn_s_setprio(1);
#pragma unroll
    for (int ksub = 0; ksub < 2; ++ksub) {
      u32 pw[8];
#pragma unroll
      for (int i = 0; i < 8; ++i) pw[i] = cvt_pk_bf16(sacc[ksub][2 * i], sacc[ksub][2 * i + 1]);
      pl32swap(pw[0], pw[2]);
      pl32swap(pw[1], pw[3]);
      pl32swap(pw[4], pw[6]);
      pl32swap(pw[5], pw[7]);
#pragma unroll
      for (int j = 0; j < 2; ++j) {
        u32x4 fw = {pw[j * 4 + 0], pw[j * 4 + 1], pw[j * 4 + 2], pw[j * 4 + 3]};
        bf16x8 pb = __builtin_bit_cast(bf16x8, fw);
#pragma unroll
        for (int dsub = 0; dsub < 4; ++dsub) {
          bf16x8 va = *(const bf16x8*)&Vlds[cur][(dsub * 32 + l31) * 64 +
                                                 ((ksub * 32 + j * 16 + hi8) ^ swV)];
          o[dsub] = __builtin_amdgcn_mfma_f32_32x32x16_bf16(va, pb, o[dsub], 0, 0, 0);
        }
      }
    }
    __builtin_amdgcn_s_setprio(0);
    SB0; BARR; SB0;
  }
  float lt = lsum + __shfl_xor(lsum, 32);
  float ri = 1.0f / lt;
  u16* op = Aout + (size_t)qrow * E_N + h * D_N;
  const int sw2 = (qrow & 7) << 3;  // GEMM-A pre-swizzle
#pragma unroll
  for (int dsub = 0; dsub < 4; ++dsub)
#pragma unroll
    for (int g = 0; g < 4; ++g) {
      int dbase = dsub * 32 + 8 * g + 4 * hi;
      u32x2 wv;
      wv[0] = (u32)f2bf(o[dsub][g * 4 + 0] * ri) | ((u32)f2bf(o[dsub][g * 4 + 1] * ri) << 16);
      wv[1] = (u32)f2bf(o[dsub][g * 4 + 2] * ri) | ((u32)f2bf(o[dsub][g * 4 + 3] * ri) << 16);
      *(u32x2*)(op + (dbase ^ sw2)) = wv;
    }
}

extern "C" void kernel_launch(void* const* d_in, const int* in_sizes, int n_in,
                              void* d_out, int out_size, void* d_ws, size_t ws_size,
                              hipStream_t stream) {
  const float* hs   = (const float*)d_in[0];
  const float* cosb = (const float*)d_in[1];
  const float* sinb = (const float*)d_in[2];
  // d_in[3] = attn_mask (causal tril — applied analytically)
  const float* qw = (const float*)d_in[4];
  const float* qb = (const float*)d_in[5];
  const float* kw = (const float*)d_in[6];
  const float* kb = (const float*)d_in[7];
  const float* vw = (const float*)d_in[8];
  const float* vb = (const float*)d_in[9];
  const float* ow = (const float*)d_in[10];
  float* outp = (float*)d_out;

  char* ws = (char*)d_ws;
  u16* hsb    = (u16*)(ws);                       // 2048x3584 bf16 (swz)           14.7MB
  u16* wt     = (u16*)(ws + 14680064);            // 4608x3584 bf16 (swz)             33MB
  u16* wt2    = (u16*)(ws + 47710208);            // 3584x3584 ow^T bf16 (swz)      25.7MB
  u16* attn_o = (u16*)(ws + 73400320);            // 2048x3584 bf16 (swz)           14.7MB
  u16* Qb     = (u16*)(ws + 88080384);            // [28][2048][128] (unroped)      14.7MB
  u16* Kb     = (u16*)(ws + 102760448);           // [4][2048][128] (swz after rope)  2MB
  u16* Vtb    = (u16*)(ws + 104857600);           // [512][2048] (swz within-64)      2MB

  // 1. hs -> bf16 (GEMM-swizzled)
  k_hs_bf16_swz<<<dim3(917504 / 256), dim3(256), 0, stream>>>(hs, hsb);
  // 2. merged qw/kw/vw/ow transposes (GEMM-swizzled)
  k_wtrans<<<dim3(128, 56), dim3(256), 0, stream>>>(qw, kw, vw, ow, wt, wt2);
  // 3. QKV GEMM, BM=160: 13x18 = 234 blocks (91% CU fill), fused bias+layout epilogue
  k_gemm<160, 1><<<dim3(234), dim3(512), 0, stream>>>(hsb, wt, nullptr, 4608, 18,
                                                      qb, kb, vb, Qb, Kb, Vtb);
  // 4. RoPE in-place on K (swizzled); Q roped in-register inside k_attn
  k_ropek<<<dim3(2048), dim3(256), 0, stream>>>(Kb, cosb, sinb);
  // 5. attention -> attn_o (bf16, GEMM-swizzled)
  k_attn<<<dim3(16, 28), dim3(256), 0, stream>>>(Qb, Kb, Vtb, cosb, sinb, attn_o);
  // 6. output projection, BM=128: 224 blocks
  k_gemm<128, 0><<<dim3(224), dim3(512), 0, stream>>>(attn_o, wt2, outp, 3584, 14,
                                                      nullptr, nullptr, nullptr,
                                                      nullptr, nullptr, nullptr);
}

// Round 15
// 237.136 us; speedup vs baseline: 1.1604x; 1.0242x over previous
//
#include <hip/hip_runtime.h>

#define H_N 28
#define KVH_N 4
#define D_N 128
#define S_N 2048
#define E_N 3584
#define NQKV 4608

typedef unsigned short u16;
typedef unsigned int u32;
typedef __bf16 bf16x8 __attribute__((ext_vector_type(8)));
typedef float f32x4 __attribute__((ext_vector_type(4)));
typedef float f32x16 __attribute__((ext_vector_type(16)));
typedef unsigned short u16x4 __attribute__((ext_vector_type(4)));
typedef unsigned short u16x8 __attribute__((ext_vector_type(8)));
typedef unsigned int u32x2 __attribute__((ext_vector_type(2)));
typedef unsigned int u32x4 __attribute__((ext_vector_type(4)));

typedef __attribute__((address_space(1))) void gvoid_t;
typedef __attribute__((address_space(3))) void lvoid_t;

static __device__ __forceinline__ u16 f2bf(float f) {
  __bf16 h = (__bf16)f;
  return __builtin_bit_cast(unsigned short, h);
}

static __device__ __forceinline__ float bf2f(u16 b) {
  u32 u = (u32)b << 16;
  return __builtin_bit_cast(float, u);
}

static __device__ __forceinline__ void gload16(const void* g, void* l) {
  __builtin_amdgcn_global_load_lds((gvoid_t*)g, (lvoid_t*)l, 16, 0, 0);
}

static __device__ __forceinline__ void gload4(const void* g, void* l) {
  __builtin_amdgcn_global_load_lds((gvoid_t*)g, (lvoid_t*)l, 4, 0, 0);
}

static __device__ __forceinline__ u32 cvt_pk_bf16(float lo, float hi) {
  u32 r;
  asm("v_cvt_pk_bf16_f32 %0, %1, %2" : "=v"(r) : "v"(lo), "v"(hi));
  return r;
}

static __device__ __forceinline__ void pl32swap(u32& a, u32& b) {
  asm volatile("v_permlane32_swap_b32 %0, %1" : "+v"(a), "+v"(b));
}

static __device__ __forceinline__ float vmax16(f32x16 v) {
  float a = fmaxf(fmaxf(v[0], v[1]), fmaxf(v[2], v[3]));
  float b = fmaxf(fmaxf(v[4], v[5]), fmaxf(v[6], v[7]));
  float c = fmaxf(fmaxf(v[8], v[9]), fmaxf(v[10], v[11]));
  float d = fmaxf(fmaxf(v[12], v[13]), fmaxf(v[14], v[15]));
  return fmaxf(fmaxf(a, b), fmaxf(c, d));
}

static __device__ __forceinline__ float vsum16(f32x16 v) {
  float a = (v[0] + v[1]) + (v[2] + v[3]);
  float b = (v[4] + v[5]) + (v[6] + v[7]);
  float c = (v[8] + v[9]) + (v[10] + v[11]);
  float d = (v[12] + v[13]) + (v[14] + v[15]);
  return (a + b) + (c + d);
}

// -------- merged prepass: qw/kw/vw/ow transposes + hs f32->bf16, one launch ----------
// bx<56: qw ; <64: kw ; <72: vw ; <128: ow ; >=128: hs conversion (lb = (bx-128)*56+by)
__global__ __launch_bounds__(256) void k_wtrans(const float* __restrict__ qw,
                                                const float* __restrict__ kw,
                                                const float* __restrict__ vw,
                                                const float* __restrict__ ow,
                                                const float* __restrict__ hs,
                                                u16* __restrict__ wt,
                                                u16* __restrict__ wt2,
                                                u16* __restrict__ hsb) {
  int bx = blockIdx.x;
  if (bx >= 128) {
    int g = ((bx - 128) * 56 + blockIdx.y) * 256 + threadIdx.x;  // 8-elem groups
    int row = g / 448, c8 = g % 448;
    const float4* p = (const float4*)(hs + (size_t)g * 8);
    float4 a = p[0], b = p[1];
    u16x8 r;
    r[0] = f2bf(a.x); r[1] = f2bf(a.y); r[2] = f2bf(a.z); r[3] = f2bf(a.w);
    r[4] = f2bf(b.x); r[5] = f2bf(b.y); r[6] = f2bf(b.z); r[7] = f2bf(b.w);
    int dc8 = c8 ^ (row & 7);
    *(u16x8*)(hsb + (size_t)row * E_N + dc8 * 8) = r;
    return;
  }
  __shared__ float t[64][65];
  const float* in;
  u16* out;
  int C, c0;
  if (bx < 56) {
    in = qw; out = wt; C = 3584; c0 = bx * 64;
  } else if (bx < 64) {
    in = kw; out = wt + (size_t)3584 * 3584; C = 512; c0 = (bx - 56) * 64;
  } else if (bx < 72) {
    in = vw; out = wt + (size_t)4096 * 3584; C = 512; c0 = (bx - 64) * 64;
  } else {
    in = ow; out = wt2; C = 3584; c0 = (bx - 72) * 64;
  }
  int r0 = blockIdx.y * 64;
  int lr = threadIdx.x >> 6, lc = threadIdx.x & 63;
#pragma unroll
  for (int i = 0; i < 64; i += 4)
    t[lr + i][lc] = in[(size_t)(r0 + lr + i) * C + c0 + lc];
  __syncthreads();
#pragma unroll
  for (int i = 0; i < 64; i += 4) {
    int orow = c0 + lr + i;
    int sw = (orow & 7) << 3;
    out[(size_t)orow * 3584 + r0 + (lc ^ sw)] = f2bf(t[lc][lr + i]);
  }
}

// =================== GEMM BMx256, BK=64, 8 waves, balanced 4-phase =====================
// BM in {128, 160, 192}. A tail (BM=160): 32-row unit staged via 2x width-4
// global_load_lds (uniform per-wave issue count). Issues/tile: 6/8/7 -> counted
// vmcnt(ISS-2) at P3 keeps exactly tile T+1 resident (FIFO-traced).
// Phases: P0 rdA-halfA+B q01; P1 rdA-halfB; P2 rdB q23; P3 none.
// Stage: P0:(T+1).B2,B3->buf^1  P1:(T+2).B0,B1  P2:(T+2).A0,A1  P3:(T+2).A2/tail
// EPI=1: fused QKV epilogue — Q (bias, unroped); K (bias + RoPE + (s&15)<<3 swizzle,
// final); V (bias, transposed + within-64 swizzle).
#define BARR __builtin_amdgcn_s_barrier()
#define SB0 __builtin_amdgcn_sched_barrier(0)
#define LGKM0 asm volatile("s_waitcnt lgkmcnt(0)" ::: "memory")
#define VMW0 asm volatile("s_waitcnt vmcnt(0)" ::: "memory")

template <int BM, int EPI>
__global__ __launch_bounds__(512, 2) void k_gemm(const u16* __restrict__ A,
                                                 const u16* __restrict__ Bt,
                                                 float* __restrict__ Cout,
                                                 int Nn, int nxt,
                                                 const float* __restrict__ qb,
                                                 const float* __restrict__ kb,
                                                 const float* __restrict__ vb,
                                                 const float* __restrict__ cosb,
                                                 const float* __restrict__ sinb,
                                                 u16* __restrict__ Qo,
                                                 u16* __restrict__ Ko,
                                                 u16* __restrict__ Vo) {
  constexpr int NA64 = BM / 64;                 // full 64-row A units
  constexpr bool HAS_A2 = (BM % 64) != 0;       // 32-row tail
  constexpr int NFR = BM / 32;                  // m-frags per wave
  constexpr int MHA = (NFR + 1) / 2;            // first-half frags
  constexpr int MHB = NFR - MHA;                // second-half frags
  constexpr int ISS = NA64 + (HAS_A2 ? 2 : 0) + 4;  // vmem issues per tile
  constexpr int LROWS = BM + 256;
  __shared__ __align__(16) u16 L[2 * LROWS * 64];
  const int K = 3584, NKT = 56;
  const int tid = threadIdx.x;
  const int lane = tid & 63;
  const int w = tid >> 6;
  const int lr = lane & 15, lh = lane >> 4, lh8 = lh * 8;
  const int swz = (lr & 7) << 3;
  const int wr = w >> 2, wc = w & 3;  // 2 M-waves x 4 N-waves

  // bijective XCD swizzle (m204)
  const int nwg = gridDim.x;
  const int bid = blockIdx.x;
  const int q8 = nwg >> 3, r8 = nwg & 7;
  const int xcd = bid & 7, idx = bid >> 3;
  const int lb = (xcd < r8 ? xcd * (q8 + 1) : r8 * (q8 + 1) + (xcd - r8) * q8) + idx;
  const size_t m0 = (size_t)(lb / nxt) * BM;
  const size_t n0 = (size_t)(lb % nxt) << 8;

  const u16* __restrict__ Ab = A + m0 * K;
  const u16* __restrict__ Bb = Bt + n0 * K;

  const int srow = tid >> 3, scol8 = tid & 7;
  auto stg = [&](int buf, int u, int kt) {  // 64-row units: u<NA64 A, else B
    if (kt >= NKT) return;
    const u16* src;
    int ldsrow;
    if (u < NA64) {
      src = Ab + (size_t)(u * 64 + srow) * K;
      ldsrow = u * 64 + srow;
    } else {
      src = Bb + (size_t)((u - NA64) * 64 + srow) * K;
      ldsrow = BM + (u - NA64) * 64 + srow;
    }
    gload16(src + kt * 64 + scol8 * 8, &L[buf * (LROWS * 64) + ldsrow * 64 + scol8 * 8]);
  };
  auto stgA2 = [&](int buf, int kt) {  // 32-row tail, 2 width-4 issues (all waves)
    if constexpr (HAS_A2) {
      if (kt >= NKT) return;
      int c2 = (tid & 31) * 2;
#pragma unroll
      for (int jj = 0; jj < 2; ++jj) {
        int rr = NA64 * 64 + jj * 16 + (tid >> 5);
        gload4(Ab + (size_t)rr * K + kt * 64 + c2,
               &L[buf * (LROWS * 64) + rr * 64 + c2]);
      }
    }
  };
  auto vmw = [&]() {
    if constexpr (ISS == 8) { asm volatile("s_waitcnt vmcnt(6)" ::: "memory"); }
    else if constexpr (ISS == 7) { asm volatile("s_waitcnt vmcnt(5)" ::: "memory"); }
    else { asm volatile("s_waitcnt vmcnt(4)" ::: "memory"); }
  };

  f32x4 acc[NFR][4];
#pragma unroll
  for (int i = 0; i < NFR; i++)
#pragma unroll
    for (int j = 0; j < 4; j++) acc[i][j] = f32x4{0.f, 0.f, 0.f, 0.f};

  bf16x8 afA[MHA][2], afB[MHB][2], bq[2][2];

  auto rdA = [&](auto& arr, int LB, int mbase) {
    constexpr int CNT = sizeof(arr) / sizeof(arr[0]);
#pragma unroll
    for (int mm = 0; mm < CNT; ++mm)
#pragma unroll
      for (int kk = 0; kk < 2; ++kk)
        arr[mm][kk] = *(const bf16x8*)&L[LB + (wr * (BM / 2) + (mbase + mm) * 16 + lr) * 64 +
                                         ((kk * 32 + lh8) ^ swz)];
  };
  auto rdB = [&](int LB, int qbase) {
#pragma unroll
    for (int j = 0; j < 2; ++j)
#pragma unroll
      for (int kk = 0; kk < 2; ++kk)
        bq[j][kk] = *(const bf16x8*)&L[LB + (BM + (qbase + j) * 64 + wc * 16 + lr) * 64 +
                                       ((kk * 32 + lh8) ^ swz)];
  };
  auto mm4 = [&](auto& af, int mbase, int qbase) {
    constexpr int CNT = sizeof(af) / sizeof(af[0]);
    __builtin_amdgcn_s_setprio(1);
#pragma unroll
    for (int mm = 0; mm < CNT; ++mm)
#pragma unroll
      for (int j = 0; j < 2; ++j)
#pragma unroll
        for (int kk = 0; kk < 2; ++kk)
          acc[mbase + mm][qbase + j] = __builtin_amdgcn_mfma_f32_16x16x32_bf16(
              af[mm][kk], bq[j][kk], acc[mbase + mm][qbase + j], 0, 0, 0);
    __builtin_amdgcn_s_setprio(0);
  };

  // prologue: tile0 all units; tile1 all except B2,B3; counted wait drains tile0.
#pragma unroll
  for (int u = 0; u < NA64 + 4; ++u) stg(0, u, 0);
  stgA2(0, 0);
  stg(1, NA64 + 0, 1); stg(1, NA64 + 1, 1);
#pragma unroll
  for (int u = 0; u < NA64; ++u) stg(1, u, 1);
  stgA2(1, 1);
  vmw();
  BARR;

  for (int T = 0; T < NKT; ++T) {
    const int cur = T & 1;
    const int LB = cur * (LROWS * 64);
    // P0
    rdA(afA, LB, 0);
    rdB(LB, 0);
    stg(cur ^ 1, NA64 + 2, T + 1);
    stg(cur ^ 1, NA64 + 3, T + 1);
    BARR; LGKM0;
    mm4(afA, 0, 0);
    BARR;
    // P1
    rdA(afB, LB, MHA);
    stg(cur, NA64 + 0, T + 2);
    stg(cur, NA64 + 1, T + 2);
    BARR; LGKM0;
    mm4(afB, MHA, 0);
    BARR;
    // P2
    rdB(LB, 2);
    stg(cur, 0, T + 2);
    stg(cur, 1, T + 2);
    BARR; LGKM0;
    mm4(afA, 0, 2);
    BARR;
    // P3
    if constexpr (NA64 == 3) stg(cur, 2, T + 2);
    stgA2(cur, T + 2);
    if (T + 2 < NKT) { vmw(); } else { VMW0; }
    BARR;
    mm4(afB, MHA, 2);
    BARR;
  }

  if constexpr (EPI == 0) {
    const size_t Nsz = (size_t)Nn;
#pragma unroll
    for (int m = 0; m < NFR; ++m) {
      size_t row = m0 + wr * (BM / 2) + m * 16 + lh * 4;
      if (row < 2048) {
#pragma unroll
        for (int p = 0; p < 4; ++p) {
          size_t col = n0 + p * 64 + wc * 16 + lr;
#pragma unroll
          for (int r = 0; r < 4; ++r) Cout[(row + r) * Nsz + col] = acc[m][p][r];
        }
      }
    }
  } else {
    const int ntile = (int)(n0 >> 8);  // 0..17
#pragma unroll
    for (int m = 0; m < NFR; ++m) {
      size_t row = m0 + wr * (BM / 2) + m * 16 + lh * 4;
      if (row >= 2048) continue;
      if (ntile < 14) {  // Q (bias only, unroped — attn ropes in-register)
#pragma unroll
        for (int p = 0; p < 4; ++p) {
          int col = (int)n0 + p * 64 + wc * 16 + lr;
          int hh = col >> 7, d = col & 127;
          float bias = qb[col];
#pragma unroll
          for (int r = 0; r < 4; ++r)
            Qo[((size_t)hh * S_N + row + r) * D_N + d] = f2bf(acc[m][p][r] + bias);
        }
      } else if (ntile < 16) {
        // K: bias + RoPE + swizzled write (FINAL). Pair (p=2pp, p=2pp+1) = (d0, d0+64)
        // of kvh = (ntile-14)*2 + pp; d0 = wc*16+lr in [0,64).
        int d0 = wc * 16 + lr;
#pragma unroll
        for (int pp = 0; pp < 2; ++pp) {
          int kvh = (ntile - 14) * 2 + pp;
          float blo = kb[kvh * 128 + d0];
          float bhi = kb[kvh * 128 + d0 + 64];
#pragma unroll
          for (int r = 0; r < 4; ++r) {
            int s = (int)row + r;
            float cl = cosb[s * D_N + d0], sl = sinb[s * D_N + d0];
            float ch = cosb[s * D_N + d0 + 64], sh = sinb[s * D_N + d0 + 64];
            float x0 = acc[m][2 * pp][r] + blo;
            float x1 = acc[m][2 * pp + 1][r] + bhi;
            float y0 = x0 * cl - x1 * sl;
            float y1 = x1 * ch + x0 * sh;
            int sw = (s & 15) << 3;
            u16* kp = Ko + ((size_t)kvh * S_N + s) * D_N;
            kp[d0 ^ sw] = f2bf(y0);
            kp[(d0 + 64) ^ sw] = f2bf(y1);
          }
        }
      } else {  // V -> transposed [cc][s], within-64 swizzle; 4-run contiguous in s
#pragma unroll
        for (int p = 0; p < 4; ++p) {
          int col = (int)n0 + p * 64 + wc * 16 + lr;
          int cc = col - 4096;
          float bias = vb[cc];
          int s = (int)row;
          int pos = (s & ~63) | ((s & 63) ^ ((cc & 7) << 3));
          u16x4 vv;
#pragma unroll
          for (int r = 0; r < 4; ++r) vv[r] = f2bf(acc[m][p][r] + bias);
          *(u16x4*)(Vo + (size_t)cc * S_N + pos) = vv;
        }
      }
    }
  }
}

// ---------------- flash attention, GQA, causal; Q-RoPE fused in prologue ----------------
// qt map: constant-sum pairing — under round-robin bid->CU, CU k hosts bids k and
// k+256; qt(h<16)=15-bx, qt(h>=16)=bx => per-CU step sum == 15 (balanced makespan).
__global__ __launch_bounds__(256, 2) void k_attn(const u16* __restrict__ Q,
                                                 const u16* __restrict__ Kc,
                                                 const u16* __restrict__ Vt,
                                                 const float* __restrict__ cosb,
                                                 const float* __restrict__ sinb,
                                                 u16* __restrict__ Aout) {
  __shared__ __align__(16) u16 Klds[2][64 * 128];
  __shared__ __align__(16) u16 Vlds[2][128 * 64];
  const int h = blockIdx.y;
  const int kvh = h / 7;  // H/KVH = 7
  const int qt = (blockIdx.y & 16) ? (blockIdx.x & 15) : ((15 - blockIdx.x) & 15);
  const int q0 = qt * 128;
  const int tid = threadIdx.x, w = tid >> 6, lane = tid & 63;
  const int l31 = lane & 31, hi = lane >> 5;
  const int hi8 = hi * 8;
  const int swK = (l31 & 15) << 3;  // K-read swizzle
  const int swV = (l31 & 7) << 3;   // V-read swizzle
  const int qloc = w * 32 + l31;
  const int qrow = q0 + qloc;

  // Q fragments with in-register RoPE: frag f (d<64) pairs with f+4 (d+64).
  bf16x8 qf[8];
  {
    const u16* qp = Q + ((size_t)h * S_N + qrow) * D_N + hi8;
    const float* cb = cosb + (size_t)qrow * D_N + hi8;
    const float* sb = sinb + (size_t)qrow * D_N + hi8;
#pragma unroll
    for (int f = 0; f < 4; ++f) {
      u16x8 ulo = __builtin_bit_cast(u16x8, *(const bf16x8*)(qp + f * 16));
      u16x8 uhi = __builtin_bit_cast(u16x8, *(const bf16x8*)(qp + (f + 4) * 16));
      u16x8 olo, ohi;
#pragma unroll
      for (int e = 0; e < 8; ++e) {
        float xl = bf2f(ulo[e]), xh = bf2f(uhi[e]);
        float cl = cb[f * 16 + e], sl = sb[f * 16 + e];
        float ch = cb[(f + 4) * 16 + e], sh = sb[(f + 4) * 16 + e];
        olo[e] = f2bf(xl * cl - xh * sl);
        ohi[e] = f2bf(xh * ch + xl * sh);
      }
      qf[f] = __builtin_bit_cast(bf16x8, olo);
      qf[f + 4] = __builtin_bit_cast(bf16x8, ohi);
    }
  }

  f32x16 o[4];
#pragma unroll
  for (int i = 0; i < 4; i++)
#pragma unroll
    for (int r = 0; r < 16; r++) o[i][r] = 0.f;

  float m2 = -3.0e38f;
  float lsum = 0.f;
  const float msc = 0.12751743f;  // 1/sqrt(128) * log2(e)

  auto stageKV = [&](int buf, int t) {
    const u16* ks = Kc + ((size_t)kvh * S_N + t * 64) * D_N;
#pragma unroll
    for (int j = 0; j < 4; ++j)
      gload16(ks + (j * 256 + tid) * 8, &Klds[buf][(j * 256 + tid) * 8]);
    const u16* vs = Vt + (size_t)kvh * D_N * S_N + t * 64;
#pragma unroll
    for (int j = 0; j < 4; ++j) {
      int idx = j * 256 + tid;
      int dd = idx >> 3, cw = idx & 7;
      gload16(vs + (size_t)dd * S_N + cw * 8, &Vlds[buf][idx * 8]);
    }
  };

  const int nt = 2 * qt + 2;
  stageKV(0, 0);
  for (int t = 0; t < nt; ++t) {
    const int cur = t & 1;
    if (t + 1 < nt) {
      stageKV(cur ^ 1, t + 1);
      asm volatile("s_waitcnt vmcnt(8)" ::: "memory");  // tile t resident (FIFO)
    } else {
      asm volatile("s_waitcnt vmcnt(0)" ::: "memory");
    }
    SB0; BARR; SB0;
    f32x16 sacc[2];
#pragma unroll
    for (int i = 0; i < 2; i++)
#pragma unroll
      for (int r = 0; r < 16; r++) sacc[i][r] = 0.f;
    __builtin_amdgcn_s_setprio(1);
#pragma unroll
    for (int dstep = 0; dstep < 8; ++dstep)
#pragma unroll
      for (int ksub = 0; ksub < 2; ++ksub) {
        bf16x8 ka =
            *(const bf16x8*)&Klds[cur][(ksub * 32 + l31) * D_N + ((dstep * 16 + hi8) ^ swK)];
        sacc[ksub] = __builtin_amdgcn_mfma_f32_32x32x16_bf16(ka, qf[dstep], sacc[ksub], 0, 0, 0);
      }
    __builtin_amdgcn_s_setprio(0);
    if (t >= nt - 2) {
#pragma unroll
      for (int ksub = 0; ksub < 2; ++ksub)
#pragma unroll
        for (int r = 0; r < 16; ++r) {
          int kvg = t * 64 + ksub * 32 + (r & 3) + 8 * (r >> 2) + 4 * hi;
          sacc[ksub][r] = (kvg <= qrow) ? sacc[ksub][r] * msc : -3.0e38f;
        }
    } else {
#pragma unroll
      for (int ksub = 0; ksub < 2; ++ksub)
#pragma unroll
        for (int r = 0; r < 16; ++r) sacc[ksub][r] *= msc;
    }
    float tmax = fmaxf(vmax16(sacc[0]), vmax16(sacc[1]));
    tmax = fmaxf(tmax, __shfl_xor(tmax, 32));  // cross-half max (known-good)
    if (__any(tmax > m2 + 8.0f)) {
      float m2new = fmaxf(m2, tmax);
      float scl = __builtin_amdgcn_exp2f(m2 - m2new);
#pragma unroll
      for (int i = 0; i < 4; i++)
#pragma unroll
        for (int r = 0; r < 16; r++) o[i][r] *= scl;
      lsum *= scl;
      m2 = m2new;
    }
#pragma unroll
    for (int ksub = 0; ksub < 2; ++ksub) {
#pragma unroll
      for (int r = 0; r < 16; ++r)
        sacc[ksub][r] = __builtin_amdgcn_exp2f(sacc[ksub][r] - m2);
      lsum += vsum16(sacc[ksub]);
    }
    __builtin_amdgcn_s_setprio(1);
#pragma unroll
    for (int ksub = 0; ksub < 2; ++ksub) {
      u32 pw[8];
#pragma unroll
      for (int i = 0; i < 8; ++i) pw[i] = cvt_pk_bf16(sacc[ksub][2 * i], sacc[ksub][2 * i + 1]);
      pl32swap(pw[0], pw[2]);
      pl32swap(pw[1], pw[3]);
      pl32swap(pw[4], pw[6]);
      pl32swap(pw[5], pw[7]);
#pragma unroll
      for (int j = 0; j < 2; ++j) {
        u32x4 fw = {pw[j * 4 + 0], pw[j * 4 + 1], pw[j * 4 + 2], pw[j * 4 + 3]};
        bf16x8 pb = __builtin_bit_cast(bf16x8, fw);
#pragma unroll
        for (int dsub = 0; dsub < 4; ++dsub) {
          bf16x8 va = *(const bf16x8*)&Vlds[cur][(dsub * 32 + l31) * 64 +
                                                 ((ksub * 32 + j * 16 + hi8) ^ swV)];
          o[dsub] = __builtin_amdgcn_mfma_f32_32x32x16_bf16(va, pb, o[dsub], 0, 0, 0);
        }
      }
    }
    __builtin_amdgcn_s_setprio(0);
    SB0; BARR; SB0;
  }
  float lt = lsum + __shfl_xor(lsum, 32);
  float ri = 1.0f / lt;
  u16* op = Aout + (size_t)qrow * E_N + h * D_N;
  const int sw2 = (qrow & 7) << 3;  // GEMM-A pre-swizzle
#pragma unroll
  for (int dsub = 0; dsub < 4; ++dsub)
#pragma unroll
    for (int g = 0; g < 4; ++g) {
      int dbase = dsub * 32 + 8 * g + 4 * hi;
      u32x2 wv;
      wv[0] = (u32)f2bf(o[dsub][g * 4 + 0] * ri) | ((u32)f2bf(o[dsub][g * 4 + 1] * ri) << 16);
      wv[1] = (u32)f2bf(o[dsub][g * 4 + 2] * ri) | ((u32)f2bf(o[dsub][g * 4 + 3] * ri) << 16);
      *(u32x2*)(op + (dbase ^ sw2)) = wv;
    }
}

extern "C" void kernel_launch(void* const* d_in, const int* in_sizes, int n_in,
                              void* d_out, int out_size, void* d_ws, size_t ws_size,
                              hipStream_t stream) {
  const float* hs   = (const float*)d_in[0];
  const float* cosb = (const float*)d_in[1];
  const float* sinb = (const float*)d_in[2];
  // d_in[3] = attn_mask (causal tril — applied analytically)
  const float* qw = (const float*)d_in[4];
  const float* qb = (const float*)d_in[5];
  const float* kw = (const float*)d_in[6];
  const float* kb = (const float*)d_in[7];
  const float* vw = (const float*)d_in[8];
  const float* vb = (const float*)d_in[9];
  const float* ow = (const float*)d_in[10];
  float* outp = (float*)d_out;

  char* ws = (char*)d_ws;
  u16* hsb    = (u16*)(ws);                       // 2048x3584 bf16 (swz)           14.7MB
  u16* wt     = (u16*)(ws + 14680064);            // 4608x3584 bf16 (swz)             33MB
  u16* wt2    = (u16*)(ws + 47710208);            // 3584x3584 ow^T bf16 (swz)      25.7MB
  u16* attn_o = (u16*)(ws + 73400320);            // 2048x3584 bf16 (swz)           14.7MB
  u16* Qb     = (u16*)(ws + 88080384);            // [28][2048][128] (unroped)      14.7MB
  u16* Kb     = (u16*)(ws + 102760448);           // [4][2048][128] (roped+swz)       2MB
  u16* Vtb    = (u16*)(ws + 104857600);           // [512][2048] (swz within-64)      2MB

  // 1. merged prepass: weight transposes + hs->bf16 (one launch)
  k_wtrans<<<dim3(192, 56), dim3(256), 0, stream>>>(qw, kw, vw, ow, hs, wt, wt2, hsb);
  // 2. QKV GEMM, BM=160 (234 blocks, 91% fill), fused bias+RoPE(K)+layout epilogue
  k_gemm<160, 1><<<dim3(234), dim3(512), 0, stream>>>(hsb, wt, nullptr, 4608, 18,
                                                      qb, kb, vb, cosb, sinb, Qb, Kb, Vtb);
  // 3. attention -> attn_o (bf16, GEMM-swizzled); Q roped in-register
  k_attn<<<dim3(16, 28), dim3(256), 0, stream>>>(Qb, Kb, Vtb, cosb, sinb, attn_o);
  // 4. output projection, BM=128 (224 blocks)
  k_gemm<128, 0><<<dim3(224), dim3(512), 0, stream>>>(attn_o, wt2, outp, 3584, 14,
                                                      nullptr, nullptr, nullptr,
                                                      nullptr, nullptr,
                                                      nullptr, nullptr, nullptr);
}